// Round 1
// 324.516 us; speedup vs baseline: 1.0269x; 1.0269x over previous
//
#include <hip/hip_runtime.h>
#include <stdint.h>

#define NUM_CLASSES 80
#define N_ANCH 25200
#define B_IMG 16
#define NMS_TOPK_ 128
#define MAX_OUT_ 100
#define SCORE_THR_ 0.25f
#define IOU_THR_ 0.45f
#define NBINS 2048
#define CAP 2048      // fallback path capacity
#define CAPB 512      // fast stage-B candidate capacity
#define CAPC 256      // stage-C capacity
#define TILE_A 80     // anchors per decode block

__constant__ float c_anch[9][2] = {
    {10.f, 13.f}, {16.f, 30.f}, {33.f, 23.f},
    {30.f, 61.f}, {62.f, 45.f}, {59.f, 119.f},
    {116.f, 90.f}, {156.f, 198.f}, {373.f, 326.f}};

__device__ __forceinline__ float sigmoidf_(float x) {
    return 1.0f / (1.0f + expf(-x));
}

__device__ __forceinline__ unsigned int score_bin(unsigned int bits) {
    // scores in (0.25, 1.0): bits in (0x3E800000, 0x3F800000)
    unsigned int bin = (bits - 0x3E800000u) >> 13;
    if (bin >= NBINS) bin = NBINS - 1;
    return bin;
}

// ============================================================================
// FAST PATH
// ============================================================================

// ---- F1: decode boxes + write transposed scores score_t[b][c][anchor] ----
// 80-anchor tiles: p3=240, p4=60, p5=15 tiles/image -> 315; float4 loads/stores.
__global__ void __launch_bounds__(256) decode_scores_kernel(
    const float* __restrict__ p3, const float* __restrict__ p4,
    const float* __restrict__ p5, float* __restrict__ boxes,
    float* __restrict__ score_t) {
    int blk = blockIdx.x;
    int b = blk / 315;
    int tile = blk - b * 315;
    const float* p; int W, lvl, il0, base;
    if (tile < 240)      { p = p3; W = 80; lvl = 0; il0 = tile * TILE_A;         base = 0;     }
    else if (tile < 300) { p = p4; W = 40; lvl = 1; il0 = (tile - 240) * TILE_A; base = 19200; }
    else                 { p = p5; W = 20; lvl = 2; il0 = (tile - 300) * TILE_A; base = 24000; }
    float stride = (float)(8 << lvl);

    __shared__ float4 raw4[TILE_A * 85 / 4];   // 27200 B
    __shared__ float obj_sh[TILE_A];
    float* raw = (float*)raw4;
    int tid = threadIdx.x;

    const float4* src4 = (const float4*)(p + (size_t)b * ((size_t)W * W * 255) +
                                         (size_t)il0 * 85);
    for (int k = tid; k < TILE_A * 85 / 4; k += 256) raw4[k] = src4[k];
    __syncthreads();

    if (tid < TILE_A) {
        int il = il0 + tid;
        int y = il / (W * 3);
        int t = il - y * (W * 3);
        int x = t / 3;
        int a = t - x * 3;
        const float* q = &raw[tid * 85];
        float cx = (sigmoidf_(q[0]) + (float)x) * stride;
        float cy = (sigmoidf_(q[1]) + (float)y) * stride;
        float bw = expf(q[2]) * c_anch[lvl * 3 + a][0];
        float bh = expf(q[3]) * c_anch[lvl * 3 + a][1];
        int gi = base + il;
        float* bo = boxes + ((size_t)b * N_ANCH + gi) * 4;
        bo[0] = cx - bw * 0.5f; bo[1] = cy - bh * 0.5f;
        bo[2] = cx + bw * 0.5f; bo[3] = cy + bh * 0.5f;
        obj_sh[tid] = sigmoidf_(q[4]);
    }
    __syncthreads();

    int gi0 = base + il0;
    // 80 classes x 20 float4 anchors = 1600 vector stores
    for (int o = tid; o < NUM_CLASSES * (TILE_A / 4); o += 256) {
        int c = o / (TILE_A / 4);
        int q = o - c * (TILE_A / 4);
        int j = q * 4;
        float4 v;
        v.x = obj_sh[j + 0] * sigmoidf_(raw[(j + 0) * 85 + 5 + c]);
        v.y = obj_sh[j + 1] * sigmoidf_(raw[(j + 1) * 85 + 5 + c]);
        v.z = obj_sh[j + 2] * sigmoidf_(raw[(j + 2) * 85 + 5 + c]);
        v.w = obj_sh[j + 3] * sigmoidf_(raw[(j + 3) * 85 + 5 + c]);
        float4* dst = (float4*)(score_t + ((size_t)(b * NUM_CLASSES + c)) * N_ANCH + gi0);
        dst[q] = v;
    }
}

// ---- F2a: per (image,class) top-128 selection (no NMS tail) ----
// Writes sorted-desc (scorebits<<32 | ~idx) keys; slots >= M zero-padded.
__global__ void __launch_bounds__(256) select_topk_kernel(
    const float* __restrict__ score_t,
    unsigned long long* __restrict__ topsel) {
    int tid = threadIdx.x;
    const float4* sc4 = (const float4*)(score_t + (size_t)blockIdx.x * N_ANCH);

    __shared__ unsigned int hist[NBINS];          // 8 KB
    __shared__ unsigned int segsum[256];          // 1 KB
    __shared__ unsigned long long sel[CAPB];      // 4 KB
    __shared__ unsigned int s_cnt;
    __shared__ int s_cut;

    for (int k = tid; k < NBINS; k += 256) hist[k] = 0u;
    if (tid == 0) s_cnt = 0u;
    __syncthreads();

    // Pass 1: histogram (coalesced float4 reads)
#pragma unroll 4
    for (int i = tid; i < N_ANCH / 4; i += 256) {
        float4 v = sc4[i];
        float vv[4] = {v.x, v.y, v.z, v.w};
#pragma unroll
        for (int k = 0; k < 4; ++k) {
            if (vv[k] > SCORE_THR_)
                atomicAdd(&hist[score_bin(__float_as_uint(vv[k]))], 1u);
        }
    }
    __syncthreads();

    // cutoff for rank 128
    unsigned int ss = 0;
    for (int k = 0; k < 8; ++k) ss += hist[tid * 8 + k];
    segsum[tid] = ss;
    __syncthreads();
    if (tid == 0) {
        unsigned int tot = 0; int cut = 0; int t = 255;
        for (; t >= 0; --t) {
            if (tot + segsum[t] >= NMS_TOPK_) break;
            tot += segsum[t];
        }
        if (t >= 0) {
            int j = 7;
            for (; j >= 0; --j) { tot += hist[t * 8 + j]; if (tot >= NMS_TOPK_) break; }
            if (j < 0) j = 0;
            cut = t * 8 + j;
        }
        s_cut = cut;
    }
    __syncthreads();
    unsigned int cutoff = (unsigned int)s_cut;

    // Pass 2: collect candidates at/above cutoff bin (re-read hits L3)
#pragma unroll 2
    for (int i = tid; i < N_ANCH / 4; i += 256) {
        float4 v = sc4[i];
        float vv[4] = {v.x, v.y, v.z, v.w};
#pragma unroll
        for (int k = 0; k < 4; ++k) {
            if (vv[k] > SCORE_THR_) {
                unsigned int bits = __float_as_uint(vv[k]);
                if (score_bin(bits) >= cutoff) {
                    unsigned int pos = atomicAdd(&s_cnt, 1u);
                    if (pos < CAPB) {
                        sel[pos] = ((unsigned long long)bits << 32) |
                                   (unsigned long long)(~(unsigned int)(i * 4 + k));
                    }
                }
            }
        }
    }
    __syncthreads();

    unsigned int M = s_cnt;
    if (M > CAPB) M = CAPB;
    unsigned int P2 = 1;
    while (P2 < M) P2 <<= 1;
    if (P2 < 2) P2 = 2;
    for (unsigned int k = M + tid; k < P2; k += 256) sel[k] = 0ull;
    __syncthreads();

    // 256-thread bitonic sort, desc order (all 4 waves active)
    for (unsigned int k = 2; k <= P2; k <<= 1) {
        for (unsigned int j = k >> 1; j > 0; j >>= 1) {
            for (unsigned int t = tid; t < (int)P2; t += 256) {
                unsigned int ixj = (unsigned int)t ^ j;
                if (ixj > (unsigned int)t) {
                    unsigned long long a0 = sel[t], b0 = sel[ixj];
                    bool desc = (((unsigned int)t & k) == 0);
                    if (desc ? (a0 < b0) : (a0 > b0)) { sel[t] = b0; sel[ixj] = a0; }
                }
            }
            __syncthreads();
        }
    }

    unsigned long long* dst = topsel + (size_t)blockIdx.x * NMS_TOPK_;
    if (tid < NMS_TOPK_) dst[tid] = ((unsigned int)tid < M) ? sel[tid] : 0ull;
}

// ---- F2b: wave-synchronous greedy NMS per (image,class), 1 wave/block ----
__global__ void __launch_bounds__(64) nms_kernel(
    const unsigned long long* __restrict__ topsel,
    const float* __restrict__ boxes,
    float* __restrict__ cls_score, float* __restrict__ cls_box) {
    int bc = blockIdx.x;
    int b = bc / NUM_CLASSES;
    unsigned int lane = threadIdx.x;

    __shared__ float bx[NMS_TOPK_][8];   // box(4) + pad; float4-aligned rows

    const unsigned long long* src = topsel + (size_t)bc * NMS_TOPK_;
    unsigned long long e0 = src[lane];
    unsigned long long e1 = src[64 + lane];

    bool k0 = (e0 != 0ull);
    bool k1 = (e1 != 0ull);

    float x00 = 0, y00 = 0, x01 = 0, y01 = 0, a0 = 0, sv0 = 0;
    float x10 = 0, y10 = 0, x11 = 0, y11 = 0, a1 = 0, sv1 = 0;
    if (k0) {
        unsigned int idx = ~((unsigned int)(e0 & 0xFFFFFFFFull));
        float4 bp = *(const float4*)(boxes + ((size_t)b * N_ANCH + idx) * 4);
        x00 = bp.x; y00 = bp.y; x01 = bp.z; y01 = bp.w;
        sv0 = __uint_as_float((unsigned int)(e0 >> 32));
        a0 = (x01 - x00) * (y01 - y00);
    }
    if (k1) {
        unsigned int idx = ~((unsigned int)(e1 & 0xFFFFFFFFull));
        float4 bp = *(const float4*)(boxes + ((size_t)b * N_ANCH + idx) * 4);
        x10 = bp.x; y10 = bp.y; x11 = bp.z; y11 = bp.w;
        sv1 = __uint_as_float((unsigned int)(e1 >> 32));
        a1 = (x11 - x10) * (y11 - y10);
    }
    {
        float4 v0 = {x00, y00, x01, y01};
        float4 v1 = {x10, y10, x11, y11};
        *(float4*)&bx[lane][0] = v0;
        *(float4*)&bx[64 + lane][0] = v1;
    }
    __syncthreads();

    unsigned long long km0 = __ballot(k0);
    unsigned long long km1 = __ballot(k1);
    for (unsigned int i = 0; i < NMS_TOPK_; ++i) {
        bool ki = ((((i < 64) ? km0 : km1) >> (i & 63)) & 1ull) != 0ull;
        if (ki) {
            float4 rb = *(const float4*)&bx[i][0];
            float ra = (rb.z - rb.x) * (rb.w - rb.y);
            if (k0 && lane > i) {
                float lx = fmaxf(rb.x, x00), ly = fmaxf(rb.y, y00);
                float rx = fminf(rb.z, x01), ry = fminf(rb.w, y01);
                float w = fmaxf(rx - lx, 0.f), h = fmaxf(ry - ly, 0.f);
                float inter = w * h;
                float iou = inter / (ra + a0 - inter + 1e-9f);
                if (iou > IOU_THR_) k0 = false;
            }
            if (k1 && (64 + lane) > i) {
                float lx = fmaxf(rb.x, x10), ly = fmaxf(rb.y, y10);
                float rx = fminf(rb.z, x11), ry = fminf(rb.w, y11);
                float w = fmaxf(rx - lx, 0.f), h = fmaxf(ry - ly, 0.f);
                float inter = w * h;
                float iou = inter / (ra + a1 - inter + 1e-9f);
                if (iou > IOU_THR_) k1 = false;
            }
            km0 = __ballot(k0);
            km1 = __ballot(k1);
        }
    }

    // Parallel compaction straight from registers
    float* scd = cls_score + (size_t)bc * MAX_OUT_;
    float* bod = cls_box + (size_t)bc * (MAX_OUT_ * 4);
    int n0 = __popcll(km0);
    int n = n0 + __popcll(km1);
    if (k0) {
        int pos = __popcll(km0 & ((1ull << lane) - 1ull));
        if (pos < MAX_OUT_) {
            scd[pos] = sv0;
            bod[pos * 4 + 0] = x00; bod[pos * 4 + 1] = y00;
            bod[pos * 4 + 2] = x01; bod[pos * 4 + 3] = y01;
        }
    }
    if (k1) {
        int pos = n0 + __popcll(km1 & ((1ull << lane) - 1ull));
        if (pos < MAX_OUT_) {
            scd[pos] = sv1;
            bod[pos * 4 + 0] = x10; bod[pos * 4 + 1] = y10;
            bod[pos * 4 + 2] = x11; bod[pos * 4 + 3] = y11;
        }
    }
    int start = n < MAX_OUT_ ? n : MAX_OUT_;
    for (int p2 = start + (int)lane; p2 < MAX_OUT_; p2 += 64) {
        scd[p2] = -1.0f;
        bod[p2 * 4 + 0] = 0.f; bod[p2 * 4 + 1] = 0.f;
        bod[p2 * 4 + 2] = 0.f; bod[p2 * 4 + 3] = 0.f;
    }
}

// ---- F2 (legacy single-kernel variant, used when ws lacks topsel space) ----
__global__ void __launch_bounds__(256) topk_nms_fast_kernel(
    const float* __restrict__ score_t, const float* __restrict__ boxes,
    float* __restrict__ cls_score, float* __restrict__ cls_box) {
    int b = blockIdx.x / NUM_CLASSES;
    int c = blockIdx.x % NUM_CLASSES;
    int tid = threadIdx.x;
    int lane = tid & 63;
    int wave = tid >> 6;
    const float4* sc4 = (const float4*)(score_t + (size_t)(b * NUM_CLASSES + c) * N_ANCH);

    __shared__ unsigned int hist[NBINS];          // 8 KB
    __shared__ unsigned int segsum[256];          // 1 KB
    __shared__ unsigned long long sel[CAPB];      // 4 KB
    __shared__ float bx[NMS_TOPK_][5];            // box(4) + score(1); pad kills conflicts
    __shared__ unsigned int s_cnt;
    __shared__ int s_cut;

    for (int k = tid; k < NBINS; k += 256) hist[k] = 0u;
    if (tid == 0) s_cnt = 0u;
    __syncthreads();

    for (int i = tid; i < N_ANCH / 4; i += 256) {
        float4 v = sc4[i];
        float vv[4] = {v.x, v.y, v.z, v.w};
#pragma unroll
        for (int k = 0; k < 4; ++k) {
            if (vv[k] > SCORE_THR_)
                atomicAdd(&hist[score_bin(__float_as_uint(vv[k]))], 1u);
        }
    }
    __syncthreads();

    unsigned int ss = 0;
    for (int k = 0; k < 8; ++k) ss += hist[tid * 8 + k];
    segsum[tid] = ss;
    __syncthreads();
    if (tid == 0) {
        unsigned int tot = 0; int cut = 0; int t = 255;
        for (; t >= 0; --t) {
            if (tot + segsum[t] >= NMS_TOPK_) break;
            tot += segsum[t];
        }
        if (t >= 0) {
            int j = 7;
            for (; j >= 0; --j) { tot += hist[t * 8 + j]; if (tot >= NMS_TOPK_) break; }
            if (j < 0) j = 0;
            cut = t * 8 + j;
        }
        s_cut = cut;
    }
    __syncthreads();
    unsigned int cutoff = (unsigned int)s_cut;

    for (int i = tid; i < N_ANCH / 4; i += 256) {
        float4 v = sc4[i];
        float vv[4] = {v.x, v.y, v.z, v.w};
#pragma unroll
        for (int k = 0; k < 4; ++k) {
            if (vv[k] > SCORE_THR_) {
                unsigned int bits = __float_as_uint(vv[k]);
                if (score_bin(bits) >= cutoff) {
                    unsigned int pos = atomicAdd(&s_cnt, 1u);
                    if (pos < CAPB) {
                        sel[pos] = ((unsigned long long)bits << 32) |
                                   (unsigned long long)(~(unsigned int)(i * 4 + k));
                    }
                }
            }
        }
    }
    __syncthreads();

    unsigned int M = s_cnt;
    if (M > CAPB) M = CAPB;
    unsigned int P2 = 1;
    while (P2 < M) P2 <<= 1;
    if (P2 < 2) P2 = 2;
    for (unsigned int k = M + tid; k < P2; k += 256) sel[k] = 0ull;
    __syncthreads();

    if (wave == 0) {
        for (unsigned int k = 2; k <= P2; k <<= 1) {
            for (unsigned int j = k >> 1; j > 0; j >>= 1) {
                for (unsigned int t = (unsigned int)lane; t < P2; t += 64) {
                    unsigned int ixj = t ^ j;
                    if (ixj > t) {
                        unsigned long long a0 = sel[t], b0 = sel[ixj];
                        bool desc = ((t & k) == 0);
                        if (desc ? (a0 < b0) : (a0 > b0)) { sel[t] = b0; sel[ixj] = a0; }
                    }
                }
                __threadfence_block();
            }
        }
    }
    __syncthreads();

    unsigned int K = M < NMS_TOPK_ ? M : NMS_TOPK_;
    if (tid < (int)K) {
        unsigned long long kk = sel[tid];
        unsigned int idx = ~((unsigned int)(kk & 0xFFFFFFFFull));
        const float* bp = boxes + ((size_t)b * N_ANCH + idx) * 4;
        bx[tid][0] = bp[0]; bx[tid][1] = bp[1];
        bx[tid][2] = bp[2]; bx[tid][3] = bp[3];
        bx[tid][4] = __uint_as_float((unsigned int)(kk >> 32));
    }
    __syncthreads();

    if (wave == 0) {
        bool k0 = (unsigned int)lane < K;
        bool k1 = (unsigned int)(64 + lane) < K;
        float x00 = 0, y00 = 0, x01 = 0, y01 = 0, a0 = 0, sv0 = 0;
        float x10 = 0, y10 = 0, x11 = 0, y11 = 0, a1 = 0, sv1 = 0;
        if (k0) {
            x00 = bx[lane][0]; y00 = bx[lane][1];
            x01 = bx[lane][2]; y01 = bx[lane][3]; sv0 = bx[lane][4];
            a0 = (x01 - x00) * (y01 - y00);
        }
        if (k1) {
            x10 = bx[64 + lane][0]; y10 = bx[64 + lane][1];
            x11 = bx[64 + lane][2]; y11 = bx[64 + lane][3]; sv1 = bx[64 + lane][4];
            a1 = (x11 - x10) * (y11 - y10);
        }
        unsigned long long km0 = __ballot(k0);
        unsigned long long km1 = __ballot(k1);
        for (unsigned int i = 0; i < K; ++i) {
            bool ki = ((((i < 64) ? km0 : km1) >> (i & 63)) & 1ull) != 0ull;
            if (ki) {
                float rx0 = bx[i][0], ry0 = bx[i][1], rx1 = bx[i][2], ry1 = bx[i][3];
                float ra = (rx1 - rx0) * (ry1 - ry0);
                if (k0 && (unsigned int)lane > i) {
                    float lx = fmaxf(rx0, x00), ly = fmaxf(ry0, y00);
                    float rx = fminf(rx1, x01), ry = fminf(ry1, y01);
                    float w = fmaxf(rx - lx, 0.f), h = fmaxf(ry - ly, 0.f);
                    float inter = w * h;
                    float iou = inter / (ra + a0 - inter + 1e-9f);
                    if (iou > IOU_THR_) k0 = false;
                }
                if (k1 && (unsigned int)(64 + lane) > i) {
                    float lx = fmaxf(rx0, x10), ly = fmaxf(ry0, y10);
                    float rx = fminf(rx1, x11), ry = fminf(ry1, y11);
                    float w = fmaxf(rx - lx, 0.f), h = fmaxf(ry - ly, 0.f);
                    float inter = w * h;
                    float iou = inter / (ra + a1 - inter + 1e-9f);
                    if (iou > IOU_THR_) k1 = false;
                }
                km0 = __ballot(k0);
                km1 = __ballot(k1);
            }
        }
        float* scd = cls_score + ((size_t)b * NUM_CLASSES + c) * MAX_OUT_;
        float* bod = cls_box + ((size_t)b * NUM_CLASSES + c) * (MAX_OUT_ * 4);
        int n0 = __popcll(km0);
        int n = n0 + __popcll(km1);
        if (k0) {
            int pos = __popcll(km0 & ((1ull << lane) - 1ull));
            if (pos < MAX_OUT_) {
                scd[pos] = sv0;
                bod[pos * 4 + 0] = x00; bod[pos * 4 + 1] = y00;
                bod[pos * 4 + 2] = x01; bod[pos * 4 + 3] = y01;
            }
        }
        if (k1) {
            int pos = n0 + __popcll(km1 & ((1ull << lane) - 1ull));
            if (pos < MAX_OUT_) {
                scd[pos] = sv1;
                bod[pos * 4 + 0] = x10; bod[pos * 4 + 1] = y10;
                bod[pos * 4 + 2] = x11; bod[pos * 4 + 3] = y11;
            }
        }
        int start = n < MAX_OUT_ ? n : MAX_OUT_;
        for (int p2 = start + lane; p2 < MAX_OUT_; p2 += 64) {
            scd[p2] = -1.0f;
            bod[p2 * 4 + 0] = 0.f; bod[p2 * 4 + 1] = 0.f;
            bod[p2 * 4 + 2] = 0.f; bod[p2 * 4 + 3] = 0.f;
        }
    }
}

// ---- F3: per-image final top-100 via histogram cutoff ----
__global__ void __launch_bounds__(256) final_fast_kernel(
    const float* __restrict__ cls_score, const float* __restrict__ cls_box,
    float* __restrict__ out) {
    int b = blockIdx.x;
    int tid = threadIdx.x;
    const int NC = NUM_CLASSES * MAX_OUT_;  // 8000
    const float* sc = cls_score + (size_t)b * NC;

    __shared__ unsigned int hist[NBINS];
    __shared__ unsigned int segsum[256];
    __shared__ unsigned long long keys[CAPC];
    __shared__ unsigned int s_cnt, s_tot;
    __shared__ int s_cut;

    for (int k = tid; k < NBINS; k += 256) hist[k] = 0u;
    if (tid == 0) s_cnt = 0u;
    __syncthreads();

    for (int k = tid; k < NC; k += 256) {
        float s = sc[k];
        if (s > 0.0f) atomicAdd(&hist[score_bin(__float_as_uint(s))], 1u);
    }
    __syncthreads();

    unsigned int ss = 0;
    for (int k = 0; k < 8; ++k) ss += hist[tid * 8 + k];
    segsum[tid] = ss;
    __syncthreads();
    if (tid == 0) {
        unsigned int total = 0;
        for (int t = 0; t < 256; ++t) total += segsum[t];
        s_tot = total;
        unsigned int tot = 0; int cut = 0; int t = 255;
        for (; t >= 0; --t) {
            if (tot + segsum[t] >= MAX_OUT_) break;
            tot += segsum[t];
        }
        if (t >= 0) {
            int j = 7;
            for (; j >= 0; --j) { tot += hist[t * 8 + j]; if (tot >= MAX_OUT_) break; }
            if (j < 0) j = 0;
            cut = t * 8 + j;
        }
        s_cut = cut;
    }
    __syncthreads();
    unsigned int cutoff = (unsigned int)s_cut;

    for (int k = tid; k < NC; k += 256) {
        float s = sc[k];
        if (s > 0.0f && score_bin(__float_as_uint(s)) >= cutoff) {
            unsigned int pos = atomicAdd(&s_cnt, 1u);
            if (pos < CAPC) {
                keys[pos] = ((unsigned long long)__float_as_uint(s) << 32) |
                            (unsigned long long)(~(unsigned int)k);
            }
        }
    }
    __syncthreads();

    unsigned int M = s_cnt;
    if (M > CAPC) M = CAPC;
    unsigned int P2 = 1;
    while (P2 < M) P2 <<= 1;
    if (P2 < 2) P2 = 2;
    for (unsigned int k = M + tid; k < P2; k += 256) keys[k] = 0ull;
    __syncthreads();

    // 256-thread bitonic sort (was 64-thread single-wave)
    for (unsigned int k = 2; k <= P2; k <<= 1) {
        for (unsigned int j = k >> 1; j > 0; j >>= 1) {
            for (unsigned int t = (unsigned int)tid; t < P2; t += 256) {
                unsigned int ixj = t ^ j;
                if (ixj > t) {
                    unsigned long long a0 = keys[t], b0 = keys[ixj];
                    bool desc = ((t & k) == 0);
                    if (desc ? (a0 < b0) : (a0 > b0)) { keys[t] = b0; keys[ixj] = a0; }
                }
            }
            __syncthreads();
        }
    }

    float* ob = out;                              // boxes  16*100*4
    float* os = out + B_IMG * MAX_OUT_ * 4;       // scores 16*100
    float* oc = os + B_IMG * MAX_OUT_;            // cls    16*100
    float* on = oc + B_IMG * MAX_OUT_;            // n_valid 16

    unsigned int K = M < MAX_OUT_ ? M : MAX_OUT_;
    if (tid < MAX_OUT_) {
        if ((unsigned int)tid < K) {
            unsigned long long kk = keys[tid];
            unsigned int flat = ~((unsigned int)(kk & 0xFFFFFFFFull));
            float sv = __uint_as_float((unsigned int)(kk >> 32));
            const float* bp = cls_box + ((size_t)b * NC + flat) * 4;
            os[b * MAX_OUT_ + tid] = sv;
            oc[b * MAX_OUT_ + tid] = (float)(flat / MAX_OUT_);
            ob[(b * MAX_OUT_ + tid) * 4 + 0] = bp[0];
            ob[(b * MAX_OUT_ + tid) * 4 + 1] = bp[1];
            ob[(b * MAX_OUT_ + tid) * 4 + 2] = bp[2];
            ob[(b * MAX_OUT_ + tid) * 4 + 3] = bp[3];
        } else {
            os[b * MAX_OUT_ + tid] = 0.0f;
            oc[b * MAX_OUT_ + tid] = 0.0f;
            ob[(b * MAX_OUT_ + tid) * 4 + 0] = 0.0f;
            ob[(b * MAX_OUT_ + tid) * 4 + 1] = 0.0f;
            ob[(b * MAX_OUT_ + tid) * 4 + 2] = 0.0f;
            ob[(b * MAX_OUT_ + tid) * 4 + 3] = 0.0f;
        }
    }
    if (tid == 0) {
        unsigned int nv = s_tot < MAX_OUT_ ? s_tot : MAX_OUT_;
        on[b] = (float)nv;
    }
}

// ============================================================================
// FALLBACK PATH (round-1, known-correct) — used when ws_size is too small
// ============================================================================

__global__ void __launch_bounds__(256) decode_kernel(
    const float* __restrict__ p3, const float* __restrict__ p4,
    const float* __restrict__ p5, float* __restrict__ boxes,
    float* __restrict__ obj) {
    int gid = blockIdx.x * blockDim.x + threadIdx.x;
    if (gid >= B_IMG * N_ANCH) return;
    int b = gid / N_ANCH;
    int i = gid - b * N_ANCH;
    const float* p; int W, il, lvl; float stride;
    if (i < 19200)      { p = p3; W = 80; il = i;         lvl = 0; stride = 8.f;  }
    else if (i < 24000) { p = p4; W = 40; il = i - 19200; lvl = 1; stride = 16.f; }
    else                { p = p5; W = 20; il = i - 24000; lvl = 2; stride = 32.f; }
    int y = il / (W * 3);
    int t = il - y * W * 3;
    int x = t / 3;
    int a = t - x * 3;
    const float* q = p + ((((size_t)b * W + y) * W + x) * 255 + a * 85);
    float cx = (sigmoidf_(q[0]) + (float)x) * stride;
    float cy = (sigmoidf_(q[1]) + (float)y) * stride;
    float bw = expf(q[2]) * c_anch[lvl * 3 + a][0];
    float bh = expf(q[3]) * c_anch[lvl * 3 + a][1];
    float* bo = boxes + (size_t)gid * 4;
    bo[0] = cx - bw * 0.5f; bo[1] = cy - bh * 0.5f;
    bo[2] = cx + bw * 0.5f; bo[3] = cy + bh * 0.5f;
    obj[gid] = sigmoidf_(q[4]);
}

__device__ __forceinline__ float cand_score(
    const float* __restrict__ p3, const float* __restrict__ p4,
    const float* __restrict__ p5, const float* __restrict__ obj,
    int b, int c, int i) {
    const float* p; int W, il;
    if (i < 19200)      { p = p3; W = 80; il = i;         }
    else if (i < 24000) { p = p4; W = 40; il = i - 19200; }
    else                { p = p5; W = 20; il = i - 24000; }
    int y = il / (W * 3);
    int t = il - y * W * 3;
    int x = t / 3;
    int a = t - x * 3;
    float cl = p[(((size_t)b * W + y) * W + x) * 255 + a * 85 + 5 + c];
    return obj[b * N_ANCH + i] * sigmoidf_(cl);
}

__global__ void __launch_bounds__(256) topk_nms_kernel(
    const float* __restrict__ p3, const float* __restrict__ p4,
    const float* __restrict__ p5, const float* __restrict__ boxes,
    const float* __restrict__ obj, float* __restrict__ cls_score,
    float* __restrict__ cls_box) {
    int b = blockIdx.x / NUM_CLASSES;
    int c = blockIdx.x % NUM_CLASSES;
    int tid = threadIdx.x;

    __shared__ unsigned int hist[NBINS];
    __shared__ unsigned long long keys[CAP];
    __shared__ unsigned int s_cnt, s_cutoff;
    __shared__ float bx[NMS_TOPK_][5];
    __shared__ float bs[NMS_TOPK_];
    __shared__ int keep[NMS_TOPK_];

    for (int k = tid; k < NBINS; k += 256) hist[k] = 0u;
    if (tid == 0) s_cnt = 0u;
    __syncthreads();

    for (int i = tid; i < N_ANCH; i += 256) {
        float s = cand_score(p3, p4, p5, obj, b, c, i);
        if (s > SCORE_THR_) atomicAdd(&hist[score_bin(__float_as_uint(s))], 1u);
    }
    __syncthreads();

    if (tid == 0) {
        unsigned int total = 0;
        int cut = 0;
        for (int k = NBINS - 1; k >= 0; --k) {
            total += hist[k];
            if (total >= NMS_TOPK_) { cut = k; break; }
        }
        s_cutoff = (unsigned int)cut;
    }
    __syncthreads();
    unsigned int cutoff = s_cutoff;

    for (int i = tid; i < N_ANCH; i += 256) {
        float s = cand_score(p3, p4, p5, obj, b, c, i);
        if (s > SCORE_THR_) {
            unsigned int bits = __float_as_uint(s);
            if (score_bin(bits) >= cutoff) {
                unsigned int pos = atomicAdd(&s_cnt, 1u);
                if (pos < CAP) {
                    keys[pos] = ((unsigned long long)bits << 32) |
                                (unsigned long long)(~(unsigned int)i);
                }
            }
        }
    }
    __syncthreads();

    unsigned int M = s_cnt;
    if (M > CAP) M = CAP;
    unsigned int P2 = 1;
    while (P2 < M) P2 <<= 1;
    if (P2 < 2) P2 = 2;
    for (unsigned int k = M + tid; k < P2; k += 256) keys[k] = 0ull;
    __syncthreads();

    for (unsigned int k = 2; k <= P2; k <<= 1) {
        for (unsigned int j = k >> 1; j > 0; j >>= 1) {
            for (unsigned int t = tid; t < P2; t += 256) {
                unsigned int ixj = t ^ j;
                if (ixj > t) {
                    unsigned long long a0 = keys[t], b0 = keys[ixj];
                    bool desc = ((t & k) == 0);
                    if (desc ? (a0 < b0) : (a0 > b0)) { keys[t] = b0; keys[ixj] = a0; }
                }
            }
            __syncthreads();
        }
    }

    unsigned int K = M < NMS_TOPK_ ? M : NMS_TOPK_;
    if (tid < (int)K) {
        unsigned long long kk = keys[tid];
        unsigned int idx = ~((unsigned int)(kk & 0xFFFFFFFFull));
        const float* bp = boxes + ((size_t)b * N_ANCH + idx) * 4;
        bx[tid][0] = bp[0]; bx[tid][1] = bp[1];
        bx[tid][2] = bp[2]; bx[tid][3] = bp[3];
        bs[tid] = __uint_as_float((unsigned int)(kk >> 32));
        keep[tid] = 1;
    }
    __syncthreads();

    for (unsigned int i = 0; i < K; ++i) {
        if (keep[i]) {
            unsigned int t = (unsigned int)tid;
            if (t > i && t < K && keep[t]) {
                float ax0 = bx[i][0], ay0 = bx[i][1], ax1 = bx[i][2], ay1 = bx[i][3];
                float cx0 = bx[t][0], cy0 = bx[t][1], cx1 = bx[t][2], cy1 = bx[t][3];
                float areaA = (ax1 - ax0) * (ay1 - ay0);
                float areaB = (cx1 - cx0) * (cy1 - cy0);
                float lx = fmaxf(ax0, cx0), ly = fmaxf(ay0, cy0);
                float rx = fminf(ax1, cx1), ry = fminf(ay1, cy1);
                float w = rx - lx; if (w < 0.f) w = 0.f;
                float h = ry - ly; if (h < 0.f) h = 0.f;
                float inter = w * h;
                float iou = inter / (areaA + areaB - inter + 1e-9f);
                if (iou > IOU_THR_) keep[t] = 0;
            }
        }
        __syncthreads();
    }

    if (tid == 0) {
        float* scd = cls_score + ((size_t)b * NUM_CLASSES + c) * MAX_OUT_;
        float* bod = cls_box + ((size_t)b * NUM_CLASSES + c) * MAX_OUT_ * 4;
        int out_n = 0;
        for (unsigned int t2 = 0; t2 < K && out_n < MAX_OUT_; ++t2) {
            if (keep[t2]) {
                scd[out_n] = bs[t2];
                bod[out_n * 4 + 0] = bx[t2][0];
                bod[out_n * 4 + 1] = bx[t2][1];
                bod[out_n * 4 + 2] = bx[t2][2];
                bod[out_n * 4 + 3] = bx[t2][3];
                out_n++;
            }
        }
        for (; out_n < MAX_OUT_; ++out_n) {
            scd[out_n] = -1.0f;
            bod[out_n * 4 + 0] = 0.f; bod[out_n * 4 + 1] = 0.f;
            bod[out_n * 4 + 2] = 0.f; bod[out_n * 4 + 3] = 0.f;
        }
    }
}

extern "C" void kernel_launch(void* const* d_in, const int* in_sizes, int n_in,
                              void* d_out, int out_size, void* d_ws, size_t ws_size,
                              hipStream_t stream) {
    const float* p3 = (const float*)d_in[0];
    const float* p4 = (const float*)d_in[1];
    const float* p5 = (const float*)d_in[2];

    const size_t score_t_elems = (size_t)B_IMG * NUM_CLASSES * N_ANCH;
    const size_t boxes_elems   = (size_t)B_IMG * N_ANCH * 4;
    const size_t clsS_elems    = (size_t)B_IMG * NUM_CLASSES * MAX_OUT_;
    const size_t clsB_elems    = clsS_elems * 4;
    const size_t topsel_bytes  = (size_t)B_IMG * NUM_CLASSES * NMS_TOPK_ *
                                 sizeof(unsigned long long);  // 1.31 MB
    const size_t need_fast = (score_t_elems + boxes_elems + clsS_elems + clsB_elems) * sizeof(float);
    const size_t need_full = need_fast + topsel_bytes;

    float* ws = (float*)d_ws;

    if (ws_size >= need_full) {
        float* score_t   = ws;
        float* boxes     = score_t + score_t_elems;
        float* cls_score = boxes + boxes_elems;
        float* cls_box   = cls_score + clsS_elems;
        unsigned long long* topsel = (unsigned long long*)(cls_box + clsB_elems);

        decode_scores_kernel<<<B_IMG * 315, 256, 0, stream>>>(p3, p4, p5, boxes, score_t);
        select_topk_kernel<<<B_IMG * NUM_CLASSES, 256, 0, stream>>>(score_t, topsel);
        nms_kernel<<<B_IMG * NUM_CLASSES, 64, 0, stream>>>(topsel, boxes, cls_score, cls_box);
        final_fast_kernel<<<B_IMG, 256, 0, stream>>>(cls_score, cls_box, (float*)d_out);
    } else if (ws_size >= need_fast) {
        float* score_t   = ws;
        float* boxes     = score_t + score_t_elems;
        float* cls_score = boxes + boxes_elems;
        float* cls_box   = cls_score + clsS_elems;

        decode_scores_kernel<<<B_IMG * 315, 256, 0, stream>>>(p3, p4, p5, boxes, score_t);
        topk_nms_fast_kernel<<<B_IMG * NUM_CLASSES, 256, 0, stream>>>(
            score_t, boxes, cls_score, cls_box);
        final_fast_kernel<<<B_IMG, 256, 0, stream>>>(cls_score, cls_box, (float*)d_out);
    } else {
        float* boxes = ws;
        float* obj = boxes + boxes_elems;
        float* cls_score = obj + (size_t)B_IMG * N_ANCH;
        float* cls_box = cls_score + clsS_elems;

        int tot = B_IMG * N_ANCH;
        decode_kernel<<<(tot + 255) / 256, 256, 0, stream>>>(p3, p4, p5, boxes, obj);
        topk_nms_kernel<<<B_IMG * NUM_CLASSES, 256, 0, stream>>>(
            p3, p4, p5, boxes, obj, cls_score, cls_box);
        final_fast_kernel<<<B_IMG, 256, 0, stream>>>(cls_score, cls_box, (float*)d_out);
    }
}

// Round 2
// 312.088 us; speedup vs baseline: 1.0678x; 1.0398x over previous
//
#include <hip/hip_runtime.h>
#include <stdint.h>

#define NUM_CLASSES 80
#define N_ANCH 25200
#define B_IMG 16
#define NMS_TOPK_ 128
#define MAX_OUT_ 100
#define SCORE_THR_ 0.25f
#define IOU_THR_ 0.45f
#define NBINS 2048      // fallback path histogram bins
#define CAP 2048        // fallback path capacity
#define CAPB 1024       // u16-select candidate capacity
#define CAPC 256        // stage-C capacity
#define U16_THR 0x3E80u // (float bits of 0.25) >> 16

__constant__ float c_anch[9][2] = {
    {10.f, 13.f}, {16.f, 30.f}, {33.f, 23.f},
    {30.f, 61.f}, {62.f, 45.f}, {59.f, 119.f},
    {116.f, 90.f}, {156.f, 198.f}, {373.f, 326.f}};

__device__ __forceinline__ float sigmoidf_(float x) {
    return 1.0f / (1.0f + expf(-x));
}

__device__ __forceinline__ unsigned int score_bin(unsigned int bits) {
    // scores in (0.25, 1.0): bits in (0x3E800000, 0x3F800000)
    unsigned int bin = (bits - 0x3E800000u) >> 13;
    if (bin >= NBINS) bin = NBINS - 1;
    return bin;
}

// ============================================================================
// FAST PATH (u16 score tensor)
// ============================================================================

// ---- F1: decode boxes + write transposed u16 scores score_u[b][c][anchor] ----
// p3: 300 tiles of 64 anchors, p4: 75x64, p5: 30x40 -> 405 tiles/image.
__global__ void __launch_bounds__(256) decode_scores_u16_kernel(
    const float* __restrict__ p3, const float* __restrict__ p4,
    const float* __restrict__ p5, float* __restrict__ boxes,
    unsigned short* __restrict__ score_u) {
    int blk = blockIdx.x;
    int b = blk / 405;
    int tile = blk - b * 405;
    const float* p; int W, lvl, il0, base, ta;
    if (tile < 300)      { p = p3; W = 80; lvl = 0; ta = 64; il0 = tile * 64;         base = 0;     }
    else if (tile < 375) { p = p4; W = 40; lvl = 1; ta = 64; il0 = (tile - 300) * 64; base = 19200; }
    else                 { p = p5; W = 20; lvl = 2; ta = 40; il0 = (tile - 375) * 40; base = 24000; }
    float stride = (float)(8 << lvl);

    __shared__ float4 raw4[64 * 85 / 4];   // 21760 B
    __shared__ float obj_sh[64];
    float* raw = (float*)raw4;
    int tid = threadIdx.x;

    const float4* src4 = (const float4*)(p + (size_t)b * ((size_t)W * W * 255) +
                                         (size_t)il0 * 85);
    int n4 = ta * 85 / 4;   // 1360 or 850
    for (int k = tid; k < n4; k += 256) raw4[k] = src4[k];
    __syncthreads();

    if (tid < ta) {
        int il = il0 + tid;
        int y = il / (W * 3);
        int t = il - y * (W * 3);
        int x = t / 3;
        int a = t - x * 3;
        const float* q = &raw[tid * 85];
        float cx = (sigmoidf_(q[0]) + (float)x) * stride;
        float cy = (sigmoidf_(q[1]) + (float)y) * stride;
        float bw = expf(q[2]) * c_anch[lvl * 3 + a][0];
        float bh = expf(q[3]) * c_anch[lvl * 3 + a][1];
        int gi = base + il;
        float* bo = boxes + ((size_t)b * N_ANCH + gi) * 4;
        bo[0] = cx - bw * 0.5f; bo[1] = cy - bh * 0.5f;
        bo[2] = cx + bw * 0.5f; bo[3] = cy + bh * 0.5f;
        obj_sh[tid] = sigmoidf_(q[4]);
    }
    __syncthreads();

    int gi0 = base + il0;
    int gpc = ta >> 3;                 // ushort8 groups per class: 8 or 5
    int ng = NUM_CLASSES * gpc;        // 640 or 400
    for (int o = tid; o < ng; o += 256) {
        int c, g;
        if (gpc == 8) { c = o >> 3; g = o & 7; }
        else          { c = o / 5;  g = o - c * 5; }
        int j = g * 8;
        unsigned int w[4];
#pragma unroll
        for (int k = 0; k < 4; ++k) {
            float s0 = obj_sh[j + 2 * k]     * sigmoidf_(raw[(j + 2 * k) * 85 + 5 + c]);
            float s1 = obj_sh[j + 2 * k + 1] * sigmoidf_(raw[(j + 2 * k + 1) * 85 + 5 + c]);
            w[k] = (__float_as_uint(s0) >> 16) | (__float_as_uint(s1) & 0xFFFF0000u);
        }
        uint4 v = {w[0], w[1], w[2], w[3]};
        *(uint4*)(score_u + ((size_t)(b * NUM_CLASSES + c)) * N_ANCH + gi0 + j) = v;
    }
}

// ---- F2a: per (image,class) top-128 selection over u16 scores ----
// Histogram cutoff on truncated scores (superset of exact top-128), then
// exact-score recompute from raw logits for the collected candidates.
__global__ void __launch_bounds__(256) select_topk_u16_kernel(
    const unsigned short* __restrict__ score_u,
    const float* __restrict__ p3, const float* __restrict__ p4,
    const float* __restrict__ p5,
    unsigned long long* __restrict__ topsel) {
    int bc = blockIdx.x;
    int b = bc / NUM_CLASSES;
    int c = bc - b * NUM_CLASSES;
    int tid = threadIdx.x;
    const uint4* sc = (const uint4*)(score_u + (size_t)bc * N_ANCH);

    __shared__ unsigned int hist[256];            // 1 KB
    __shared__ unsigned long long sel[CAPB];      // 8 KB
    __shared__ unsigned int s_cnt;
    __shared__ int s_cut;

    hist[tid] = 0u;
    if (tid == 0) s_cnt = 0u;
    __syncthreads();

    // Pass 1: histogram of truncated scores (coalesced 16B reads, 8 u16/load)
    for (int i = tid; i < N_ANCH / 8; i += 256) {
        uint4 v = sc[i];
        unsigned int ww[4] = {v.x, v.y, v.z, v.w};
#pragma unroll
        for (int k = 0; k < 8; ++k) {
            unsigned int h = (ww[k >> 1] >> ((k & 1) * 16)) & 0xFFFFu;
            if (h >= U16_THR) {
                unsigned int bin = h - U16_THR;
                if (bin > 255u) bin = 255u;
                atomicAdd(&hist[bin], 1u);
            }
        }
    }
    __syncthreads();

    if (tid == 0) {
        unsigned int tot = 0; int cut = 0;
        for (int t = 255; t >= 0; --t) {
            tot += hist[t];
            if (tot >= NMS_TOPK_) { cut = t; break; }
        }
        s_cut = cut;
    }
    __syncthreads();
    unsigned int cutoff = (unsigned int)s_cut;

    // Pass 2: collect candidate indices at/above cutoff bin (L3-warm re-read)
    for (int i = tid; i < N_ANCH / 8; i += 256) {
        uint4 v = sc[i];
        unsigned int ww[4] = {v.x, v.y, v.z, v.w};
#pragma unroll
        for (int k = 0; k < 8; ++k) {
            unsigned int h = (ww[k >> 1] >> ((k & 1) * 16)) & 0xFFFFu;
            if (h >= U16_THR) {
                unsigned int bin = h - U16_THR;
                if (bin > 255u) bin = 255u;
                if (bin >= cutoff) {
                    unsigned int pos = atomicAdd(&s_cnt, 1u);
                    if (pos < CAPB) sel[pos] = (unsigned long long)(i * 8 + k);
                }
            }
        }
    }
    __syncthreads();

    unsigned int M = s_cnt;
    if (M > CAPB) M = CAPB;

    // Exact-score recompute (bitwise identical formula to decode) + key build
    for (unsigned int t = tid; t < M; t += 256) {
        unsigned int idx = (unsigned int)sel[t];
        const float* q;
        if (idx < 19200u)      q = p3 + (size_t)b * 1632000 + (size_t)idx * 85;
        else if (idx < 24000u) q = p4 + (size_t)b * 408000 + (size_t)(idx - 19200u) * 85;
        else                   q = p5 + (size_t)b * 102000 + (size_t)(idx - 24000u) * 85;
        float s = sigmoidf_(q[4]) * sigmoidf_(q[5 + c]);
        sel[t] = (s > SCORE_THR_)
                     ? (((unsigned long long)__float_as_uint(s) << 32) |
                        (unsigned long long)(~idx))
                     : 0ull;
    }
    __syncthreads();

    unsigned int P2 = 1;
    while (P2 < M) P2 <<= 1;
    if (P2 < 2) P2 = 2;
    for (unsigned int k = M + tid; k < P2; k += 256) sel[k] = 0ull;
    __syncthreads();

    // 256-thread bitonic sort, desc order
    for (unsigned int k = 2; k <= P2; k <<= 1) {
        for (unsigned int j = k >> 1; j > 0; j >>= 1) {
            for (unsigned int t = tid; t < (int)P2; t += 256) {
                unsigned int ixj = (unsigned int)t ^ j;
                if (ixj > (unsigned int)t) {
                    unsigned long long a0 = sel[t], b0 = sel[ixj];
                    bool desc = (((unsigned int)t & k) == 0);
                    if (desc ? (a0 < b0) : (a0 > b0)) { sel[t] = b0; sel[ixj] = a0; }
                }
            }
            __syncthreads();
        }
    }

    unsigned long long* dst = topsel + (size_t)bc * NMS_TOPK_;
    if (tid < NMS_TOPK_) dst[tid] = ((unsigned int)tid < M) ? sel[tid] : 0ull;
}

// ---- F2b: wave-synchronous greedy NMS per (image,class), 1 wave/block ----
__global__ void __launch_bounds__(64) nms_kernel(
    const unsigned long long* __restrict__ topsel,
    const float* __restrict__ boxes,
    float* __restrict__ cls_score, float* __restrict__ cls_box) {
    int bc = blockIdx.x;
    int b = bc / NUM_CLASSES;
    unsigned int lane = threadIdx.x;

    __shared__ float bx[NMS_TOPK_][8];   // box(4) + pad; float4-aligned rows

    const unsigned long long* src = topsel + (size_t)bc * NMS_TOPK_;
    unsigned long long e0 = src[lane];
    unsigned long long e1 = src[64 + lane];

    bool k0 = (e0 != 0ull);
    bool k1 = (e1 != 0ull);

    float x00 = 0, y00 = 0, x01 = 0, y01 = 0, a0 = 0, sv0 = 0;
    float x10 = 0, y10 = 0, x11 = 0, y11 = 0, a1 = 0, sv1 = 0;
    if (k0) {
        unsigned int idx = ~((unsigned int)(e0 & 0xFFFFFFFFull));
        float4 bp = *(const float4*)(boxes + ((size_t)b * N_ANCH + idx) * 4);
        x00 = bp.x; y00 = bp.y; x01 = bp.z; y01 = bp.w;
        sv0 = __uint_as_float((unsigned int)(e0 >> 32));
        a0 = (x01 - x00) * (y01 - y00);
    }
    if (k1) {
        unsigned int idx = ~((unsigned int)(e1 & 0xFFFFFFFFull));
        float4 bp = *(const float4*)(boxes + ((size_t)b * N_ANCH + idx) * 4);
        x10 = bp.x; y10 = bp.y; x11 = bp.z; y11 = bp.w;
        sv1 = __uint_as_float((unsigned int)(e1 >> 32));
        a1 = (x11 - x10) * (y11 - y10);
    }
    {
        float4 v0 = {x00, y00, x01, y01};
        float4 v1 = {x10, y10, x11, y11};
        *(float4*)&bx[lane][0] = v0;
        *(float4*)&bx[64 + lane][0] = v1;
    }
    __syncthreads();

    unsigned long long km0 = __ballot(k0);
    unsigned long long km1 = __ballot(k1);
    for (unsigned int i = 0; i < NMS_TOPK_; ++i) {
        bool ki = ((((i < 64) ? km0 : km1) >> (i & 63)) & 1ull) != 0ull;
        if (ki) {
            float4 rb = *(const float4*)&bx[i][0];
            float ra = (rb.z - rb.x) * (rb.w - rb.y);
            if (k0 && lane > i) {
                float lx = fmaxf(rb.x, x00), ly = fmaxf(rb.y, y00);
                float rx = fminf(rb.z, x01), ry = fminf(rb.w, y01);
                float w = fmaxf(rx - lx, 0.f), h = fmaxf(ry - ly, 0.f);
                float inter = w * h;
                float iou = inter / (ra + a0 - inter + 1e-9f);
                if (iou > IOU_THR_) k0 = false;
            }
            if (k1 && (64 + lane) > i) {
                float lx = fmaxf(rb.x, x10), ly = fmaxf(rb.y, y10);
                float rx = fminf(rb.z, x11), ry = fminf(rb.w, y11);
                float w = fmaxf(rx - lx, 0.f), h = fmaxf(ry - ly, 0.f);
                float inter = w * h;
                float iou = inter / (ra + a1 - inter + 1e-9f);
                if (iou > IOU_THR_) k1 = false;
            }
            km0 = __ballot(k0);
            km1 = __ballot(k1);
        }
    }

    // Parallel compaction straight from registers
    float* scd = cls_score + (size_t)bc * MAX_OUT_;
    float* bod = cls_box + (size_t)bc * (MAX_OUT_ * 4);
    int n0 = __popcll(km0);
    int n = n0 + __popcll(km1);
    if (k0) {
        int pos = __popcll(km0 & ((1ull << lane) - 1ull));
        if (pos < MAX_OUT_) {
            scd[pos] = sv0;
            bod[pos * 4 + 0] = x00; bod[pos * 4 + 1] = y00;
            bod[pos * 4 + 2] = x01; bod[pos * 4 + 3] = y01;
        }
    }
    if (k1) {
        int pos = n0 + __popcll(km1 & ((1ull << lane) - 1ull));
        if (pos < MAX_OUT_) {
            scd[pos] = sv1;
            bod[pos * 4 + 0] = x10; bod[pos * 4 + 1] = y10;
            bod[pos * 4 + 2] = x11; bod[pos * 4 + 3] = y11;
        }
    }
    int start = n < MAX_OUT_ ? n : MAX_OUT_;
    for (int p2 = start + (int)lane; p2 < MAX_OUT_; p2 += 64) {
        scd[p2] = -1.0f;
        bod[p2 * 4 + 0] = 0.f; bod[p2 * 4 + 1] = 0.f;
        bod[p2 * 4 + 2] = 0.f; bod[p2 * 4 + 3] = 0.f;
    }
}

// ---- F3: per-image final top-100 via histogram cutoff ----
__global__ void __launch_bounds__(256) final_fast_kernel(
    const float* __restrict__ cls_score, const float* __restrict__ cls_box,
    float* __restrict__ out) {
    int b = blockIdx.x;
    int tid = threadIdx.x;
    const int NC = NUM_CLASSES * MAX_OUT_;  // 8000
    const float* sc = cls_score + (size_t)b * NC;

    __shared__ unsigned int hist[NBINS];
    __shared__ unsigned int segsum[256];
    __shared__ unsigned long long keys[CAPC];
    __shared__ unsigned int s_cnt, s_tot;
    __shared__ int s_cut;

    for (int k = tid; k < NBINS; k += 256) hist[k] = 0u;
    if (tid == 0) s_cnt = 0u;
    __syncthreads();

    for (int k = tid; k < NC; k += 256) {
        float s = sc[k];
        if (s > 0.0f) atomicAdd(&hist[score_bin(__float_as_uint(s))], 1u);
    }
    __syncthreads();

    unsigned int ss = 0;
    for (int k = 0; k < 8; ++k) ss += hist[tid * 8 + k];
    segsum[tid] = ss;
    __syncthreads();
    if (tid == 0) {
        unsigned int total = 0;
        for (int t = 0; t < 256; ++t) total += segsum[t];
        s_tot = total;
        unsigned int tot = 0; int cut = 0; int t = 255;
        for (; t >= 0; --t) {
            if (tot + segsum[t] >= MAX_OUT_) break;
            tot += segsum[t];
        }
        if (t >= 0) {
            int j = 7;
            for (; j >= 0; --j) { tot += hist[t * 8 + j]; if (tot >= MAX_OUT_) break; }
            if (j < 0) j = 0;
            cut = t * 8 + j;
        }
        s_cut = cut;
    }
    __syncthreads();
    unsigned int cutoff = (unsigned int)s_cut;

    for (int k = tid; k < NC; k += 256) {
        float s = sc[k];
        if (s > 0.0f && score_bin(__float_as_uint(s)) >= cutoff) {
            unsigned int pos = atomicAdd(&s_cnt, 1u);
            if (pos < CAPC) {
                keys[pos] = ((unsigned long long)__float_as_uint(s) << 32) |
                            (unsigned long long)(~(unsigned int)k);
            }
        }
    }
    __syncthreads();

    unsigned int M = s_cnt;
    if (M > CAPC) M = CAPC;
    unsigned int P2 = 1;
    while (P2 < M) P2 <<= 1;
    if (P2 < 2) P2 = 2;
    for (unsigned int k = M + tid; k < P2; k += 256) keys[k] = 0ull;
    __syncthreads();

    for (unsigned int k = 2; k <= P2; k <<= 1) {
        for (unsigned int j = k >> 1; j > 0; j >>= 1) {
            for (unsigned int t = (unsigned int)tid; t < P2; t += 256) {
                unsigned int ixj = t ^ j;
                if (ixj > t) {
                    unsigned long long a0 = keys[t], b0 = keys[ixj];
                    bool desc = ((t & k) == 0);
                    if (desc ? (a0 < b0) : (a0 > b0)) { keys[t] = b0; keys[ixj] = a0; }
                }
            }
            __syncthreads();
        }
    }

    float* ob = out;                              // boxes  16*100*4
    float* os = out + B_IMG * MAX_OUT_ * 4;       // scores 16*100
    float* oc = os + B_IMG * MAX_OUT_;            // cls    16*100
    float* on = oc + B_IMG * MAX_OUT_;            // n_valid 16

    unsigned int K = M < MAX_OUT_ ? M : MAX_OUT_;
    if (tid < MAX_OUT_) {
        if ((unsigned int)tid < K) {
            unsigned long long kk = keys[tid];
            unsigned int flat = ~((unsigned int)(kk & 0xFFFFFFFFull));
            float sv = __uint_as_float((unsigned int)(kk >> 32));
            const float* bp = cls_box + ((size_t)b * NC + flat) * 4;
            os[b * MAX_OUT_ + tid] = sv;
            oc[b * MAX_OUT_ + tid] = (float)(flat / MAX_OUT_);
            ob[(b * MAX_OUT_ + tid) * 4 + 0] = bp[0];
            ob[(b * MAX_OUT_ + tid) * 4 + 1] = bp[1];
            ob[(b * MAX_OUT_ + tid) * 4 + 2] = bp[2];
            ob[(b * MAX_OUT_ + tid) * 4 + 3] = bp[3];
        } else {
            os[b * MAX_OUT_ + tid] = 0.0f;
            oc[b * MAX_OUT_ + tid] = 0.0f;
            ob[(b * MAX_OUT_ + tid) * 4 + 0] = 0.0f;
            ob[(b * MAX_OUT_ + tid) * 4 + 1] = 0.0f;
            ob[(b * MAX_OUT_ + tid) * 4 + 2] = 0.0f;
            ob[(b * MAX_OUT_ + tid) * 4 + 3] = 0.0f;
        }
    }
    if (tid == 0) {
        unsigned int nv = s_tot < MAX_OUT_ ? s_tot : MAX_OUT_;
        on[b] = (float)nv;
    }
}

// ============================================================================
// FALLBACK PATH (round-1, known-correct) — used when ws_size is too small
// ============================================================================

__global__ void __launch_bounds__(256) decode_kernel(
    const float* __restrict__ p3, const float* __restrict__ p4,
    const float* __restrict__ p5, float* __restrict__ boxes,
    float* __restrict__ obj) {
    int gid = blockIdx.x * blockDim.x + threadIdx.x;
    if (gid >= B_IMG * N_ANCH) return;
    int b = gid / N_ANCH;
    int i = gid - b * N_ANCH;
    const float* p; int W, il, lvl; float stride;
    if (i < 19200)      { p = p3; W = 80; il = i;         lvl = 0; stride = 8.f;  }
    else if (i < 24000) { p = p4; W = 40; il = i - 19200; lvl = 1; stride = 16.f; }
    else                { p = p5; W = 20; il = i - 24000; lvl = 2; stride = 32.f; }
    int y = il / (W * 3);
    int t = il - y * W * 3;
    int x = t / 3;
    int a = t - x * 3;
    const float* q = p + ((((size_t)b * W + y) * W + x) * 255 + a * 85);
    float cx = (sigmoidf_(q[0]) + (float)x) * stride;
    float cy = (sigmoidf_(q[1]) + (float)y) * stride;
    float bw = expf(q[2]) * c_anch[lvl * 3 + a][0];
    float bh = expf(q[3]) * c_anch[lvl * 3 + a][1];
    float* bo = boxes + (size_t)gid * 4;
    bo[0] = cx - bw * 0.5f; bo[1] = cy - bh * 0.5f;
    bo[2] = cx + bw * 0.5f; bo[3] = cy + bh * 0.5f;
    obj[gid] = sigmoidf_(q[4]);
}

__device__ __forceinline__ float cand_score(
    const float* __restrict__ p3, const float* __restrict__ p4,
    const float* __restrict__ p5, const float* __restrict__ obj,
    int b, int c, int i) {
    const float* p; int W, il;
    if (i < 19200)      { p = p3; W = 80; il = i;         }
    else if (i < 24000) { p = p4; W = 40; il = i - 19200; }
    else                { p = p5; W = 20; il = i - 24000; }
    int y = il / (W * 3);
    int t = il - y * W * 3;
    int x = t / 3;
    int a = t - x * 3;
    float cl = p[(((size_t)b * W + y) * W + x) * 255 + a * 85 + 5 + c];
    return obj[b * N_ANCH + i] * sigmoidf_(cl);
}

__global__ void __launch_bounds__(256) topk_nms_kernel(
    const float* __restrict__ p3, const float* __restrict__ p4,
    const float* __restrict__ p5, const float* __restrict__ boxes,
    const float* __restrict__ obj, float* __restrict__ cls_score,
    float* __restrict__ cls_box) {
    int b = blockIdx.x / NUM_CLASSES;
    int c = blockIdx.x % NUM_CLASSES;
    int tid = threadIdx.x;

    __shared__ unsigned int hist[NBINS];
    __shared__ unsigned long long keys[CAP];
    __shared__ unsigned int s_cnt, s_cutoff;
    __shared__ float bx[NMS_TOPK_][5];
    __shared__ float bs[NMS_TOPK_];
    __shared__ int keep[NMS_TOPK_];

    for (int k = tid; k < NBINS; k += 256) hist[k] = 0u;
    if (tid == 0) s_cnt = 0u;
    __syncthreads();

    for (int i = tid; i < N_ANCH; i += 256) {
        float s = cand_score(p3, p4, p5, obj, b, c, i);
        if (s > SCORE_THR_) atomicAdd(&hist[score_bin(__float_as_uint(s))], 1u);
    }
    __syncthreads();

    if (tid == 0) {
        unsigned int total = 0;
        int cut = 0;
        for (int k = NBINS - 1; k >= 0; --k) {
            total += hist[k];
            if (total >= NMS_TOPK_) { cut = k; break; }
        }
        s_cutoff = (unsigned int)cut;
    }
    __syncthreads();
    unsigned int cutoff = s_cutoff;

    for (int i = tid; i < N_ANCH; i += 256) {
        float s = cand_score(p3, p4, p5, obj, b, c, i);
        if (s > SCORE_THR_) {
            unsigned int bits = __float_as_uint(s);
            if (score_bin(bits) >= cutoff) {
                unsigned int pos = atomicAdd(&s_cnt, 1u);
                if (pos < CAP) {
                    keys[pos] = ((unsigned long long)bits << 32) |
                                (unsigned long long)(~(unsigned int)i);
                }
            }
        }
    }
    __syncthreads();

    unsigned int M = s_cnt;
    if (M > CAP) M = CAP;
    unsigned int P2 = 1;
    while (P2 < M) P2 <<= 1;
    if (P2 < 2) P2 = 2;
    for (unsigned int k = M + tid; k < P2; k += 256) keys[k] = 0ull;
    __syncthreads();

    for (unsigned int k = 2; k <= P2; k <<= 1) {
        for (unsigned int j = k >> 1; j > 0; j >>= 1) {
            for (unsigned int t = tid; t < P2; t += 256) {
                unsigned int ixj = t ^ j;
                if (ixj > t) {
                    unsigned long long a0 = keys[t], b0 = keys[ixj];
                    bool desc = ((t & k) == 0);
                    if (desc ? (a0 < b0) : (a0 > b0)) { keys[t] = b0; keys[ixj] = a0; }
                }
            }
            __syncthreads();
        }
    }

    unsigned int K = M < NMS_TOPK_ ? M : NMS_TOPK_;
    if (tid < (int)K) {
        unsigned long long kk = keys[tid];
        unsigned int idx = ~((unsigned int)(kk & 0xFFFFFFFFull));
        const float* bp = boxes + ((size_t)b * N_ANCH + idx) * 4;
        bx[tid][0] = bp[0]; bx[tid][1] = bp[1];
        bx[tid][2] = bp[2]; bx[tid][3] = bp[3];
        bs[tid] = __uint_as_float((unsigned int)(kk >> 32));
        keep[tid] = 1;
    }
    __syncthreads();

    for (unsigned int i = 0; i < K; ++i) {
        if (keep[i]) {
            unsigned int t = (unsigned int)tid;
            if (t > i && t < K && keep[t]) {
                float ax0 = bx[i][0], ay0 = bx[i][1], ax1 = bx[i][2], ay1 = bx[i][3];
                float cx0 = bx[t][0], cy0 = bx[t][1], cx1 = bx[t][2], cy1 = bx[t][3];
                float areaA = (ax1 - ax0) * (ay1 - ay0);
                float areaB = (cx1 - cx0) * (cy1 - cy0);
                float lx = fmaxf(ax0, cx0), ly = fmaxf(ay0, cy0);
                float rx = fminf(ax1, cx1), ry = fminf(ay1, cy1);
                float w = rx - lx; if (w < 0.f) w = 0.f;
                float h = ry - ly; if (h < 0.f) h = 0.f;
                float inter = w * h;
                float iou = inter / (areaA + areaB - inter + 1e-9f);
                if (iou > IOU_THR_) keep[t] = 0;
            }
        }
        __syncthreads();
    }

    if (tid == 0) {
        float* scd = cls_score + ((size_t)b * NUM_CLASSES + c) * MAX_OUT_;
        float* bod = cls_box + ((size_t)b * NUM_CLASSES + c) * MAX_OUT_ * 4;
        int out_n = 0;
        for (unsigned int t2 = 0; t2 < K && out_n < MAX_OUT_; ++t2) {
            if (keep[t2]) {
                scd[out_n] = bs[t2];
                bod[out_n * 4 + 0] = bx[t2][0];
                bod[out_n * 4 + 1] = bx[t2][1];
                bod[out_n * 4 + 2] = bx[t2][2];
                bod[out_n * 4 + 3] = bx[t2][3];
                out_n++;
            }
        }
        for (; out_n < MAX_OUT_; ++out_n) {
            scd[out_n] = -1.0f;
            bod[out_n * 4 + 0] = 0.f; bod[out_n * 4 + 1] = 0.f;
            bod[out_n * 4 + 2] = 0.f; bod[out_n * 4 + 3] = 0.f;
        }
    }
}

extern "C" void kernel_launch(void* const* d_in, const int* in_sizes, int n_in,
                              void* d_out, int out_size, void* d_ws, size_t ws_size,
                              hipStream_t stream) {
    const float* p3 = (const float*)d_in[0];
    const float* p4 = (const float*)d_in[1];
    const float* p5 = (const float*)d_in[2];

    const size_t boxesB  = (size_t)B_IMG * N_ANCH * 4 * sizeof(float);          // 6,451,200
    const size_t clsSB   = (size_t)B_IMG * NUM_CLASSES * MAX_OUT_ * sizeof(float); // 512,000
    const size_t clsBB   = clsSB * 4;                                            // 2,048,000
    const size_t topselB = (size_t)B_IMG * NUM_CLASSES * NMS_TOPK_ * 8;          // 1,310,720
    const size_t scoreUB = (size_t)B_IMG * NUM_CLASSES * N_ANCH * 2;             // 64,512,000
    const size_t need_new = boxesB + clsSB + clsBB + topselB + scoreUB;          // ~74.8 MB

    char* base = (char*)d_ws;

    if (ws_size >= need_new) {
        float* boxes     = (float*)base;
        float* cls_score = (float*)(base + boxesB);
        float* cls_box   = (float*)(base + boxesB + clsSB);
        unsigned long long* topsel =
            (unsigned long long*)(base + boxesB + clsSB + clsBB);
        unsigned short* score_u =
            (unsigned short*)(base + boxesB + clsSB + clsBB + topselB);

        decode_scores_u16_kernel<<<B_IMG * 405, 256, 0, stream>>>(
            p3, p4, p5, boxes, score_u);
        select_topk_u16_kernel<<<B_IMG * NUM_CLASSES, 256, 0, stream>>>(
            score_u, p3, p4, p5, topsel);
        nms_kernel<<<B_IMG * NUM_CLASSES, 64, 0, stream>>>(
            topsel, boxes, cls_score, cls_box);
        final_fast_kernel<<<B_IMG, 256, 0, stream>>>(cls_score, cls_box, (float*)d_out);
    } else {
        float* boxes = (float*)base;
        float* obj = boxes + (size_t)B_IMG * N_ANCH * 4;
        float* cls_score = obj + (size_t)B_IMG * N_ANCH;
        float* cls_box = cls_score + (size_t)B_IMG * NUM_CLASSES * MAX_OUT_;

        int tot = B_IMG * N_ANCH;
        decode_kernel<<<(tot + 255) / 256, 256, 0, stream>>>(p3, p4, p5, boxes, obj);
        topk_nms_kernel<<<B_IMG * NUM_CLASSES, 256, 0, stream>>>(
            p3, p4, p5, boxes, obj, cls_score, cls_box);
        final_fast_kernel<<<B_IMG, 256, 0, stream>>>(cls_score, cls_box, (float*)d_out);
    }
}

// Round 4
// 310.199 us; speedup vs baseline: 1.0743x; 1.0061x over previous
//
#include <hip/hip_runtime.h>
#include <stdint.h>

#define NUM_CLASSES 80
#define N_ANCH 25200
#define B_IMG 16
#define NMS_TOPK_ 128
#define MAX_OUT_ 100
#define SCORE_THR_ 0.25f
#define IOU_THR_ 0.45f
#define NBINS 2048      // fallback path histogram bins
#define CAP 2048        // fallback path capacity
#define CAPB 1024       // u16-select candidate capacity
#define CAPC 256        // stage-C capacity
#define U16_THR 0x3E80u // (float bits of 0.25) >> 16
#define CHUNKS_PER_IMG 1575   // 25200 / 16

__constant__ float c_anch[9][2] = {
    {10.f, 13.f}, {16.f, 30.f}, {33.f, 23.f},
    {30.f, 61.f}, {62.f, 45.f}, {59.f, 119.f},
    {116.f, 90.f}, {156.f, 198.f}, {373.f, 326.f}};

__device__ __forceinline__ float sigmoidf_(float x) {
    return 1.0f / (1.0f + expf(-x));
}

__device__ __forceinline__ unsigned int score_bin(unsigned int bits) {
    // scores in (0.25, 1.0): bits in (0x3E800000, 0x3F800000)
    unsigned int bin = (bits - 0x3E800000u) >> 13;
    if (bin >= NBINS) bin = NBINS - 1;
    return bin;
}

// ============================================================================
// FAST PATH (u16 score tensor, wave-autonomous decode)
// ============================================================================

// ---- F1: wave-autonomous decode. Each wave owns 16 anchors; no block
// barriers (wave-lockstep + __threadfence_block = lgkmcnt drain).
__global__ void __launch_bounds__(256) decode_wave_kernel(
    const float* __restrict__ p3, const float* __restrict__ p4,
    const float* __restrict__ p5, float* __restrict__ boxes,
    unsigned short* __restrict__ score_u) {
    int wave = threadIdx.x >> 6;
    int lane = threadIdx.x & 63;
    int chunk = blockIdx.x * 4 + wave;           // 0 .. 25199
    int b = chunk / CHUNKS_PER_IMG;
    int ci = chunk - b * CHUNKS_PER_IMG;
    const float* p; int W, lvl, il0, base;
    if (ci < 1200)      { p = p3; W = 80; lvl = 0; il0 = ci * 16;          base = 0;     }
    else if (ci < 1500) { p = p4; W = 40; lvl = 1; il0 = (ci - 1200) * 16; base = 19200; }
    else                { p = p5; W = 20; lvl = 2; il0 = (ci - 1500) * 16; base = 24000; }
    float stride = (float)(8 << lvl);

    __shared__ float raw_s[4][16 * 85];   // 4 x 5440 B = 21760 B
    __shared__ float obj_s[4][16];
    float* raw = raw_s[wave];
    float* obj_sh = obj_s[wave];

    // Stage this wave's 16 anchors (1360 floats = 340 float4, coalesced).
    // NOTE: 6 iterations — 340 float4 needs ceil(340/64)=6 rounds (r3 bug was 5).
    {
        const float4* src4 = (const float4*)(p + (size_t)b * ((size_t)W * W * 255) +
                                             (size_t)il0 * 85);
        float4* raw4 = (float4*)raw;
#pragma unroll
        for (int k = 0; k < 6; ++k) {
            int idx = lane + k * 64;
            if (idx < 340) raw4[idx] = src4[idx];
        }
    }
    __threadfence_block();   // drain ds_writes: wave-wide LDS visibility

    // Box phase: 4 lanes per anchor, one box component each (coalesced 256 B)
    {
        int a = lane >> 2;           // 0..15
        int comp = lane & 3;
        int il = il0 + a;
        int y = il / (W * 3);
        int t = il - y * (W * 3);
        int x = t / 3;
        int an = t - x * 3;
        const float* q = &raw[a * 85];
        float cx = (sigmoidf_(q[0]) + (float)x) * stride;
        float cy = (sigmoidf_(q[1]) + (float)y) * stride;
        float bw = expf(q[2]) * c_anch[lvl * 3 + an][0];
        float bh = expf(q[3]) * c_anch[lvl * 3 + an][1];
        float v;
        if (comp == 0)      v = cx - bw * 0.5f;
        else if (comp == 1) v = cy - bh * 0.5f;
        else if (comp == 2) v = cx + bw * 0.5f;
        else                v = cy + bh * 0.5f;
        boxes[((size_t)b * N_ANCH + base + il) * 4 + comp] = v;
        if (comp == 0) obj_sh[a] = sigmoidf_(q[4]);
    }
    __threadfence_block();   // obj_sh visible wave-wide

    // Score phase: lane = (class c0 = lane>>1, anchor-half h = lane&1);
    // 3 iterations cover 80 classes (last one half-active).
    int gi0 = base + il0;
    int h = lane & 1;
    int c0 = lane >> 1;
    int j0 = h * 8;
#pragma unroll
    for (int it = 0; it < 3; ++it) {
        int c = it * 32 + c0;
        if (c < NUM_CLASSES) {
            unsigned int w[4];
#pragma unroll
            for (int k = 0; k < 4; ++k) {
                int j = j0 + 2 * k;
                float s0 = obj_sh[j]     * sigmoidf_(raw[j * 85 + 5 + c]);
                float s1 = obj_sh[j + 1] * sigmoidf_(raw[(j + 1) * 85 + 5 + c]);
                w[k] = (__float_as_uint(s0) >> 16) | (__float_as_uint(s1) & 0xFFFF0000u);
            }
            uint4 v = {w[0], w[1], w[2], w[3]};
            *(uint4*)(score_u + ((size_t)(b * NUM_CLASSES + c)) * N_ANCH + gi0 + j0) = v;
        }
    }
}

// ---- F2a: per (image,class) top-128 selection over u16 scores ----
// Histogram cutoff on truncated scores (superset of exact top-128), then
// exact-score recompute from raw logits for the collected candidates.
__global__ void __launch_bounds__(256) select_topk_u16_kernel(
    const unsigned short* __restrict__ score_u,
    const float* __restrict__ p3, const float* __restrict__ p4,
    const float* __restrict__ p5,
    unsigned long long* __restrict__ topsel) {
    int bc = blockIdx.x;
    int b = bc / NUM_CLASSES;
    int c = bc - b * NUM_CLASSES;
    int tid = threadIdx.x;
    int wave = tid >> 6;
    const uint4* sc = (const uint4*)(score_u + (size_t)bc * N_ANCH);

    __shared__ unsigned int hist[4][256];         // per-wave copies, 4 KB
    __shared__ unsigned long long sel[CAPB];      // 8 KB
    __shared__ unsigned int s_cnt;
    __shared__ int s_cut;

#pragma unroll
    for (int wv = 0; wv < 4; ++wv) hist[wv][tid & 255] = 0u;
    if (tid == 0) s_cnt = 0u;
    __syncthreads();

    // Pass 1: histogram of truncated scores (coalesced 16B reads, 8 u16/load)
    unsigned int* myhist = hist[wave];
    for (int i = tid; i < N_ANCH / 8; i += 256) {
        uint4 v = sc[i];
        unsigned int ww[4] = {v.x, v.y, v.z, v.w};
#pragma unroll
        for (int k = 0; k < 8; ++k) {
            unsigned int hh = (ww[k >> 1] >> ((k & 1) * 16)) & 0xFFFFu;
            if (hh >= U16_THR) {
                unsigned int bin = hh - U16_THR;
                if (bin > 255u) bin = 255u;
                atomicAdd(&myhist[bin], 1u);
            }
        }
    }
    __syncthreads();

    // merge per-wave copies into hist[0][*]
    {
        unsigned int m = hist[0][tid] + hist[1][tid] + hist[2][tid] + hist[3][tid];
        hist[0][tid] = m;
    }
    __syncthreads();

    if (tid == 0) {
        unsigned int tot = 0; int cut = 0;
        for (int t = 255; t >= 0; --t) {
            tot += hist[0][t];
            if (tot >= NMS_TOPK_) { cut = t; break; }
        }
        s_cut = cut;
    }
    __syncthreads();
    unsigned int cutoff = (unsigned int)s_cut;

    // Pass 2: collect candidate indices at/above cutoff bin (L3-warm re-read)
    for (int i = tid; i < N_ANCH / 8; i += 256) {
        uint4 v = sc[i];
        unsigned int ww[4] = {v.x, v.y, v.z, v.w};
#pragma unroll
        for (int k = 0; k < 8; ++k) {
            unsigned int hh = (ww[k >> 1] >> ((k & 1) * 16)) & 0xFFFFu;
            if (hh >= U16_THR) {
                unsigned int bin = hh - U16_THR;
                if (bin > 255u) bin = 255u;
                if (bin >= cutoff) {
                    unsigned int pos = atomicAdd(&s_cnt, 1u);
                    if (pos < CAPB) sel[pos] = (unsigned long long)(i * 8 + k);
                }
            }
        }
    }
    __syncthreads();

    unsigned int M = s_cnt;
    if (M > CAPB) M = CAPB;

    // Exact-score recompute (bitwise identical formula to decode) + key build
    for (unsigned int t = tid; t < M; t += 256) {
        unsigned int idx = (unsigned int)sel[t];
        const float* q;
        if (idx < 19200u)      q = p3 + (size_t)b * 1632000 + (size_t)idx * 85;
        else if (idx < 24000u) q = p4 + (size_t)b * 408000 + (size_t)(idx - 19200u) * 85;
        else                   q = p5 + (size_t)b * 102000 + (size_t)(idx - 24000u) * 85;
        float s = sigmoidf_(q[4]) * sigmoidf_(q[5 + c]);
        sel[t] = (s > SCORE_THR_)
                     ? (((unsigned long long)__float_as_uint(s) << 32) |
                        (unsigned long long)(~idx))
                     : 0ull;
    }
    __syncthreads();

    unsigned int P2 = 1;
    while (P2 < M) P2 <<= 1;
    if (P2 < 2) P2 = 2;
    for (unsigned int k = M + tid; k < P2; k += 256) sel[k] = 0ull;
    __syncthreads();

    // 256-thread bitonic sort, desc order
    for (unsigned int k = 2; k <= P2; k <<= 1) {
        for (unsigned int j = k >> 1; j > 0; j >>= 1) {
            for (unsigned int t = tid; t < (int)P2; t += 256) {
                unsigned int ixj = (unsigned int)t ^ j;
                if (ixj > (unsigned int)t) {
                    unsigned long long a0 = sel[t], b0 = sel[ixj];
                    bool desc = (((unsigned int)t & k) == 0);
                    if (desc ? (a0 < b0) : (a0 > b0)) { sel[t] = b0; sel[ixj] = a0; }
                }
            }
            __syncthreads();
        }
    }

    unsigned long long* dst = topsel + (size_t)bc * NMS_TOPK_;
    if (tid < NMS_TOPK_) dst[tid] = ((unsigned int)tid < M) ? sel[tid] : 0ull;
}

// ---- F2b: wave-synchronous greedy NMS per (image,class), 1 wave/block ----
__global__ void __launch_bounds__(64) nms_kernel(
    const unsigned long long* __restrict__ topsel,
    const float* __restrict__ boxes,
    float* __restrict__ cls_score, float* __restrict__ cls_box) {
    int bc = blockIdx.x;
    int b = bc / NUM_CLASSES;
    unsigned int lane = threadIdx.x;

    __shared__ float bx[NMS_TOPK_][8];   // box(4) + pad; float4-aligned rows

    const unsigned long long* src = topsel + (size_t)bc * NMS_TOPK_;
    unsigned long long e0 = src[lane];
    unsigned long long e1 = src[64 + lane];

    bool k0 = (e0 != 0ull);
    bool k1 = (e1 != 0ull);

    float x00 = 0, y00 = 0, x01 = 0, y01 = 0, a0 = 0, sv0 = 0;
    float x10 = 0, y10 = 0, x11 = 0, y11 = 0, a1 = 0, sv1 = 0;
    if (k0) {
        unsigned int idx = ~((unsigned int)(e0 & 0xFFFFFFFFull));
        float4 bp = *(const float4*)(boxes + ((size_t)b * N_ANCH + idx) * 4);
        x00 = bp.x; y00 = bp.y; x01 = bp.z; y01 = bp.w;
        sv0 = __uint_as_float((unsigned int)(e0 >> 32));
        a0 = (x01 - x00) * (y01 - y00);
    }
    if (k1) {
        unsigned int idx = ~((unsigned int)(e1 & 0xFFFFFFFFull));
        float4 bp = *(const float4*)(boxes + ((size_t)b * N_ANCH + idx) * 4);
        x10 = bp.x; y10 = bp.y; x11 = bp.z; y11 = bp.w;
        sv1 = __uint_as_float((unsigned int)(e1 >> 32));
        a1 = (x11 - x10) * (y11 - y10);
    }
    {
        float4 v0 = {x00, y00, x01, y01};
        float4 v1 = {x10, y10, x11, y11};
        *(float4*)&bx[lane][0] = v0;
        *(float4*)&bx[64 + lane][0] = v1;
    }
    __syncthreads();

    unsigned long long km0 = __ballot(k0);
    unsigned long long km1 = __ballot(k1);
    for (unsigned int i = 0; i < NMS_TOPK_; ++i) {
        bool ki = ((((i < 64) ? km0 : km1) >> (i & 63)) & 1ull) != 0ull;
        if (ki) {
            float4 rb = *(const float4*)&bx[i][0];
            float ra = (rb.z - rb.x) * (rb.w - rb.y);
            if (k0 && lane > i) {
                float lx = fmaxf(rb.x, x00), ly = fmaxf(rb.y, y00);
                float rx = fminf(rb.z, x01), ry = fminf(rb.w, y01);
                float w = fmaxf(rx - lx, 0.f), h = fmaxf(ry - ly, 0.f);
                float inter = w * h;
                float iou = inter / (ra + a0 - inter + 1e-9f);
                if (iou > IOU_THR_) k0 = false;
            }
            if (k1 && (64 + lane) > i) {
                float lx = fmaxf(rb.x, x10), ly = fmaxf(rb.y, y10);
                float rx = fminf(rb.z, x11), ry = fminf(rb.w, y11);
                float w = fmaxf(rx - lx, 0.f), h = fmaxf(ry - ly, 0.f);
                float inter = w * h;
                float iou = inter / (ra + a1 - inter + 1e-9f);
                if (iou > IOU_THR_) k1 = false;
            }
            km0 = __ballot(k0);
            km1 = __ballot(k1);
        }
    }

    // Parallel compaction straight from registers
    float* scd = cls_score + (size_t)bc * MAX_OUT_;
    float* bod = cls_box + (size_t)bc * (MAX_OUT_ * 4);
    int n0 = __popcll(km0);
    int n = n0 + __popcll(km1);
    if (k0) {
        int pos = __popcll(km0 & ((1ull << lane) - 1ull));
        if (pos < MAX_OUT_) {
            scd[pos] = sv0;
            bod[pos * 4 + 0] = x00; bod[pos * 4 + 1] = y00;
            bod[pos * 4 + 2] = x01; bod[pos * 4 + 3] = y01;
        }
    }
    if (k1) {
        int pos = n0 + __popcll(km1 & ((1ull << lane) - 1ull));
        if (pos < MAX_OUT_) {
            scd[pos] = sv1;
            bod[pos * 4 + 0] = x10; bod[pos * 4 + 1] = y10;
            bod[pos * 4 + 2] = x11; bod[pos * 4 + 3] = y11;
        }
    }
    int start = n < MAX_OUT_ ? n : MAX_OUT_;
    for (int p2 = start + (int)lane; p2 < MAX_OUT_; p2 += 64) {
        scd[p2] = -1.0f;
        bod[p2 * 4 + 0] = 0.f; bod[p2 * 4 + 1] = 0.f;
        bod[p2 * 4 + 2] = 0.f; bod[p2 * 4 + 3] = 0.f;
    }
}

// ---- F3: per-image final top-100 via histogram cutoff ----
__global__ void __launch_bounds__(256) final_fast_kernel(
    const float* __restrict__ cls_score, const float* __restrict__ cls_box,
    float* __restrict__ out) {
    int b = blockIdx.x;
    int tid = threadIdx.x;
    const int NC = NUM_CLASSES * MAX_OUT_;  // 8000
    const float* sc = cls_score + (size_t)b * NC;

    __shared__ unsigned int hist[NBINS];
    __shared__ unsigned int segsum[256];
    __shared__ unsigned long long keys[CAPC];
    __shared__ unsigned int s_cnt, s_tot;
    __shared__ int s_cut;

    for (int k = tid; k < NBINS; k += 256) hist[k] = 0u;
    if (tid == 0) s_cnt = 0u;
    __syncthreads();

    for (int k = tid; k < NC; k += 256) {
        float s = sc[k];
        if (s > 0.0f) atomicAdd(&hist[score_bin(__float_as_uint(s))], 1u);
    }
    __syncthreads();

    unsigned int ss = 0;
    for (int k = 0; k < 8; ++k) ss += hist[tid * 8 + k];
    segsum[tid] = ss;
    __syncthreads();
    if (tid == 0) {
        unsigned int total = 0;
        for (int t = 0; t < 256; ++t) total += segsum[t];
        s_tot = total;
        unsigned int tot = 0; int cut = 0; int t = 255;
        for (; t >= 0; --t) {
            if (tot + segsum[t] >= MAX_OUT_) break;
            tot += segsum[t];
        }
        if (t >= 0) {
            int j = 7;
            for (; j >= 0; --j) { tot += hist[t * 8 + j]; if (tot >= MAX_OUT_) break; }
            if (j < 0) j = 0;
            cut = t * 8 + j;
        }
        s_cut = cut;
    }
    __syncthreads();
    unsigned int cutoff = (unsigned int)s_cut;

    for (int k = tid; k < NC; k += 256) {
        float s = sc[k];
        if (s > 0.0f && score_bin(__float_as_uint(s)) >= cutoff) {
            unsigned int pos = atomicAdd(&s_cnt, 1u);
            if (pos < CAPC) {
                keys[pos] = ((unsigned long long)__float_as_uint(s) << 32) |
                            (unsigned long long)(~(unsigned int)k);
            }
        }
    }
    __syncthreads();

    unsigned int M = s_cnt;
    if (M > CAPC) M = CAPC;
    unsigned int P2 = 1;
    while (P2 < M) P2 <<= 1;
    if (P2 < 2) P2 = 2;
    for (unsigned int k = M + tid; k < P2; k += 256) keys[k] = 0ull;
    __syncthreads();

    for (unsigned int k = 2; k <= P2; k <<= 1) {
        for (unsigned int j = k >> 1; j > 0; j >>= 1) {
            for (unsigned int t = (unsigned int)tid; t < P2; t += 256) {
                unsigned int ixj = t ^ j;
                if (ixj > t) {
                    unsigned long long a0 = keys[t], b0 = keys[ixj];
                    bool desc = ((t & k) == 0);
                    if (desc ? (a0 < b0) : (a0 > b0)) { keys[t] = b0; keys[ixj] = a0; }
                }
            }
            __syncthreads();
        }
    }

    float* ob = out;                              // boxes  16*100*4
    float* os = out + B_IMG * MAX_OUT_ * 4;       // scores 16*100
    float* oc = os + B_IMG * MAX_OUT_;            // cls    16*100
    float* on = oc + B_IMG * MAX_OUT_;            // n_valid 16

    unsigned int K = M < MAX_OUT_ ? M : MAX_OUT_;
    if (tid < MAX_OUT_) {
        if ((unsigned int)tid < K) {
            unsigned long long kk = keys[tid];
            unsigned int flat = ~((unsigned int)(kk & 0xFFFFFFFFull));
            float sv = __uint_as_float((unsigned int)(kk >> 32));
            const float* bp = cls_box + ((size_t)b * NC + flat) * 4;
            os[b * MAX_OUT_ + tid] = sv;
            oc[b * MAX_OUT_ + tid] = (float)(flat / MAX_OUT_);
            ob[(b * MAX_OUT_ + tid) * 4 + 0] = bp[0];
            ob[(b * MAX_OUT_ + tid) * 4 + 1] = bp[1];
            ob[(b * MAX_OUT_ + tid) * 4 + 2] = bp[2];
            ob[(b * MAX_OUT_ + tid) * 4 + 3] = bp[3];
        } else {
            os[b * MAX_OUT_ + tid] = 0.0f;
            oc[b * MAX_OUT_ + tid] = 0.0f;
            ob[(b * MAX_OUT_ + tid) * 4 + 0] = 0.0f;
            ob[(b * MAX_OUT_ + tid) * 4 + 1] = 0.0f;
            ob[(b * MAX_OUT_ + tid) * 4 + 2] = 0.0f;
            ob[(b * MAX_OUT_ + tid) * 4 + 3] = 0.0f;
        }
    }
    if (tid == 0) {
        unsigned int nv = s_tot < MAX_OUT_ ? s_tot : MAX_OUT_;
        on[b] = (float)nv;
    }
}

// ============================================================================
// FALLBACK PATH (round-1, known-correct) — used when ws_size is too small
// ============================================================================

__global__ void __launch_bounds__(256) decode_kernel(
    const float* __restrict__ p3, const float* __restrict__ p4,
    const float* __restrict__ p5, float* __restrict__ boxes,
    float* __restrict__ obj) {
    int gid = blockIdx.x * blockDim.x + threadIdx.x;
    if (gid >= B_IMG * N_ANCH) return;
    int b = gid / N_ANCH;
    int i = gid - b * N_ANCH;
    const float* p; int W, il, lvl; float stride;
    if (i < 19200)      { p = p3; W = 80; il = i;         lvl = 0; stride = 8.f;  }
    else if (i < 24000) { p = p4; W = 40; il = i - 19200; lvl = 1; stride = 16.f; }
    else                { p = p5; W = 20; il = i - 24000; lvl = 2; stride = 32.f; }
    int y = il / (W * 3);
    int t = il - y * W * 3;
    int x = t / 3;
    int a = t - x * 3;
    const float* q = p + ((((size_t)b * W + y) * W + x) * 255 + a * 85);
    float cx = (sigmoidf_(q[0]) + (float)x) * stride;
    float cy = (sigmoidf_(q[1]) + (float)y) * stride;
    float bw = expf(q[2]) * c_anch[lvl * 3 + a][0];
    float bh = expf(q[3]) * c_anch[lvl * 3 + a][1];
    float* bo = boxes + (size_t)gid * 4;
    bo[0] = cx - bw * 0.5f; bo[1] = cy - bh * 0.5f;
    bo[2] = cx + bw * 0.5f; bo[3] = cy + bh * 0.5f;
    obj[gid] = sigmoidf_(q[4]);
}

__device__ __forceinline__ float cand_score(
    const float* __restrict__ p3, const float* __restrict__ p4,
    const float* __restrict__ p5, const float* __restrict__ obj,
    int b, int c, int i) {
    const float* p; int W, il;
    if (i < 19200)      { p = p3; W = 80; il = i;         }
    else if (i < 24000) { p = p4; W = 40; il = i - 19200; }
    else                { p = p5; W = 20; il = i - 24000; }
    int y = il / (W * 3);
    int t = il - y * W * 3;
    int x = t / 3;
    int a = t - x * 3;
    float cl = p[(((size_t)b * W + y) * W + x) * 255 + a * 85 + 5 + c];
    return obj[b * N_ANCH + i] * sigmoidf_(cl);
}

__global__ void __launch_bounds__(256) topk_nms_kernel(
    const float* __restrict__ p3, const float* __restrict__ p4,
    const float* __restrict__ p5, const float* __restrict__ boxes,
    const float* __restrict__ obj, float* __restrict__ cls_score,
    float* __restrict__ cls_box) {
    int b = blockIdx.x / NUM_CLASSES;
    int c = blockIdx.x % NUM_CLASSES;
    int tid = threadIdx.x;

    __shared__ unsigned int hist[NBINS];
    __shared__ unsigned long long keys[CAP];
    __shared__ unsigned int s_cnt, s_cutoff;
    __shared__ float bx[NMS_TOPK_][5];
    __shared__ float bs[NMS_TOPK_];
    __shared__ int keep[NMS_TOPK_];

    for (int k = tid; k < NBINS; k += 256) hist[k] = 0u;
    if (tid == 0) s_cnt = 0u;
    __syncthreads();

    for (int i = tid; i < N_ANCH; i += 256) {
        float s = cand_score(p3, p4, p5, obj, b, c, i);
        if (s > SCORE_THR_) atomicAdd(&hist[score_bin(__float_as_uint(s))], 1u);
    }
    __syncthreads();

    if (tid == 0) {
        unsigned int total = 0;
        int cut = 0;
        for (int k = NBINS - 1; k >= 0; --k) {
            total += hist[k];
            if (total >= NMS_TOPK_) { cut = k; break; }
        }
        s_cutoff = (unsigned int)cut;
    }
    __syncthreads();
    unsigned int cutoff = s_cutoff;

    for (int i = tid; i < N_ANCH; i += 256) {
        float s = cand_score(p3, p4, p5, obj, b, c, i);
        if (s > SCORE_THR_) {
            unsigned int bits = __float_as_uint(s);
            if (score_bin(bits) >= cutoff) {
                unsigned int pos = atomicAdd(&s_cnt, 1u);
                if (pos < CAP) {
                    keys[pos] = ((unsigned long long)bits << 32) |
                                (unsigned long long)(~(unsigned int)i);
                }
            }
        }
    }
    __syncthreads();

    unsigned int M = s_cnt;
    if (M > CAP) M = CAP;
    unsigned int P2 = 1;
    while (P2 < M) P2 <<= 1;
    if (P2 < 2) P2 = 2;
    for (unsigned int k = M + tid; k < P2; k += 256) keys[k] = 0ull;
    __syncthreads();

    for (unsigned int k = 2; k <= P2; k <<= 1) {
        for (unsigned int j = k >> 1; j > 0; j >>= 1) {
            for (unsigned int t = tid; t < P2; t += 256) {
                unsigned int ixj = t ^ j;
                if (ixj > t) {
                    unsigned long long a0 = keys[t], b0 = keys[ixj];
                    bool desc = ((t & k) == 0);
                    if (desc ? (a0 < b0) : (a0 > b0)) { keys[t] = b0; keys[ixj] = a0; }
                }
            }
            __syncthreads();
        }
    }

    unsigned int K = M < NMS_TOPK_ ? M : NMS_TOPK_;
    if (tid < (int)K) {
        unsigned long long kk = keys[tid];
        unsigned int idx = ~((unsigned int)(kk & 0xFFFFFFFFull));
        const float* bp = boxes + ((size_t)b * N_ANCH + idx) * 4;
        bx[tid][0] = bp[0]; bx[tid][1] = bp[1];
        bx[tid][2] = bp[2]; bx[tid][3] = bp[3];
        bs[tid] = __uint_as_float((unsigned int)(kk >> 32));
        keep[tid] = 1;
    }
    __syncthreads();

    for (unsigned int i = 0; i < K; ++i) {
        if (keep[i]) {
            unsigned int t = (unsigned int)tid;
            if (t > i && t < K && keep[t]) {
                float ax0 = bx[i][0], ay0 = bx[i][1], ax1 = bx[i][2], ay1 = bx[i][3];
                float cx0 = bx[t][0], cy0 = bx[t][1], cx1 = bx[t][2], cy1 = bx[t][3];
                float areaA = (ax1 - ax0) * (ay1 - ay0);
                float areaB = (cx1 - cx0) * (cy1 - cy0);
                float lx = fmaxf(ax0, cx0), ly = fmaxf(ay0, cy0);
                float rx = fminf(ax1, cx1), ry = fminf(ay1, cy1);
                float w = rx - lx; if (w < 0.f) w = 0.f;
                float h = ry - ly; if (h < 0.f) h = 0.f;
                float inter = w * h;
                float iou = inter / (areaA + areaB - inter + 1e-9f);
                if (iou > IOU_THR_) keep[t] = 0;
            }
        }
        __syncthreads();
    }

    if (tid == 0) {
        float* scd = cls_score + ((size_t)b * NUM_CLASSES + c) * MAX_OUT_;
        float* bod = cls_box + ((size_t)b * NUM_CLASSES + c) * MAX_OUT_ * 4;
        int out_n = 0;
        for (unsigned int t2 = 0; t2 < K && out_n < MAX_OUT_; ++t2) {
            if (keep[t2]) {
                scd[out_n] = bs[t2];
                bod[out_n * 4 + 0] = bx[t2][0];
                bod[out_n * 4 + 1] = bx[t2][1];
                bod[out_n * 4 + 2] = bx[t2][2];
                bod[out_n * 4 + 3] = bx[t2][3];
                out_n++;
            }
        }
        for (; out_n < MAX_OUT_; ++out_n) {
            scd[out_n] = -1.0f;
            bod[out_n * 4 + 0] = 0.f; bod[out_n * 4 + 1] = 0.f;
            bod[out_n * 4 + 2] = 0.f; bod[out_n * 4 + 3] = 0.f;
        }
    }
}

extern "C" void kernel_launch(void* const* d_in, const int* in_sizes, int n_in,
                              void* d_out, int out_size, void* d_ws, size_t ws_size,
                              hipStream_t stream) {
    const float* p3 = (const float*)d_in[0];
    const float* p4 = (const float*)d_in[1];
    const float* p5 = (const float*)d_in[2];

    const size_t boxesB  = (size_t)B_IMG * N_ANCH * 4 * sizeof(float);          // 6,451,200
    const size_t clsSB   = (size_t)B_IMG * NUM_CLASSES * MAX_OUT_ * sizeof(float); // 512,000
    const size_t clsBB   = clsSB * 4;                                            // 2,048,000
    const size_t topselB = (size_t)B_IMG * NUM_CLASSES * NMS_TOPK_ * 8;          // 1,310,720
    const size_t scoreUB = (size_t)B_IMG * NUM_CLASSES * N_ANCH * 2;             // 64,512,000
    const size_t need_new = boxesB + clsSB + clsBB + topselB + scoreUB;          // ~74.8 MB

    char* base = (char*)d_ws;

    if (ws_size >= need_new) {
        float* boxes     = (float*)base;
        float* cls_score = (float*)(base + boxesB);
        float* cls_box   = (float*)(base + boxesB + clsSB);
        unsigned long long* topsel =
            (unsigned long long*)(base + boxesB + clsSB + clsBB);
        unsigned short* score_u =
            (unsigned short*)(base + boxesB + clsSB + clsBB + topselB);

        decode_wave_kernel<<<(B_IMG * CHUNKS_PER_IMG) / 4, 256, 0, stream>>>(
            p3, p4, p5, boxes, score_u);
        select_topk_u16_kernel<<<B_IMG * NUM_CLASSES, 256, 0, stream>>>(
            score_u, p3, p4, p5, topsel);
        nms_kernel<<<B_IMG * NUM_CLASSES, 64, 0, stream>>>(
            topsel, boxes, cls_score, cls_box);
        final_fast_kernel<<<B_IMG, 256, 0, stream>>>(cls_score, cls_box, (float*)d_out);
    } else {
        float* boxes = (float*)base;
        float* obj = boxes + (size_t)B_IMG * N_ANCH * 4;
        float* cls_score = obj + (size_t)B_IMG * N_ANCH;
        float* cls_box = cls_score + (size_t)B_IMG * NUM_CLASSES * MAX_OUT_;

        int tot = B_IMG * N_ANCH;
        decode_kernel<<<(tot + 255) / 256, 256, 0, stream>>>(p3, p4, p5, boxes, obj);
        topk_nms_kernel<<<B_IMG * NUM_CLASSES, 256, 0, stream>>>(
            p3, p4, p5, boxes, obj, cls_score, cls_box);
        final_fast_kernel<<<B_IMG, 256, 0, stream>>>(cls_score, cls_box, (float*)d_out);
    }
}

// Round 5
// 298.089 us; speedup vs baseline: 1.1180x; 1.0406x over previous
//
#include <hip/hip_runtime.h>
#include <stdint.h>

#define NUM_CLASSES 80
#define N_ANCH 25200
#define B_IMG 16
#define NMS_TOPK_ 128
#define MAX_OUT_ 100
#define SCORE_THR_ 0.25f
#define IOU_THR_ 0.45f
#define NBINS 2048      // fallback path histogram bins
#define CAP 2048        // fallback path capacity
#define CAPB 1024       // u8-select candidate capacity
#define CAPC 256        // stage-C capacity
#define U8_BASE 0x3E7Eu // 2-ulp margin below u16(0.25)=0x3E80 (screening only)
#define CHUNKS_PER_IMG 1575   // 25200 / 16

__constant__ float c_anch[9][2] = {
    {10.f, 13.f}, {16.f, 30.f}, {33.f, 23.f},
    {30.f, 61.f}, {62.f, 45.f}, {59.f, 119.f},
    {116.f, 90.f}, {156.f, 198.f}, {373.f, 326.f}};

// Exact sigmoid — used for box decode and for the exact re-scoring of
// selected candidates (must match the jax reference bitwise-closely).
__device__ __forceinline__ float sigmoidf_(float x) {
    return 1.0f / (1.0f + expf(-x));
}

// Fast screening sigmoid (~4 inst: v_exp + v_rcp based). |err| <= ~3e-7.
// ONLY used to build the u8 screening tensor; never reaches the output.
__device__ __forceinline__ float fast_sigmoid_(float x) {
    float t = __expf(-x);
    return __fdividef(1.0f, 1.0f + t);
}

// Map score to u8 screening bin. 0 = below ~0.2485 (margin), 1..255 above.
// Monotone truncation of the fp32 bit pattern; scores in (0.25,1.0) span
// u16 0x3E80..0x3F7F, so 8 bits capture the full u16 resolution.
__device__ __forceinline__ unsigned int score_u8_(float s) {
    unsigned int u = __float_as_uint(s) >> 16;
    int bin = (int)u - (int)U8_BASE;
    if (bin < 0) bin = 0;
    if (bin > 255) bin = 255;
    return (unsigned int)bin;
}

__device__ __forceinline__ unsigned int score_bin(unsigned int bits) {
    // fallback path: scores in (0.25, 1.0): bits in (0x3E800000, 0x3F800000)
    unsigned int bin = (bits - 0x3E800000u) >> 13;
    if (bin >= NBINS) bin = NBINS - 1;
    return bin;
}

// ============================================================================
// FAST PATH (u8 screening tensor, wave-autonomous decode, exact re-score)
// ============================================================================

// ---- F1: wave-autonomous decode. Each wave owns 16 anchors.
// Boxes: exact math (output-bearing). Scores: fast-sigmoid u8 screening.
__global__ void __launch_bounds__(256) decode_wave_kernel(
    const float* __restrict__ p3, const float* __restrict__ p4,
    const float* __restrict__ p5, float* __restrict__ boxes,
    unsigned char* __restrict__ score_u8) {
    int wave = threadIdx.x >> 6;
    int lane = threadIdx.x & 63;
    int chunk = blockIdx.x * 4 + wave;           // 0 .. 25199
    int b = chunk / CHUNKS_PER_IMG;
    int ci = chunk - b * CHUNKS_PER_IMG;
    const float* p; int W, lvl, il0, base;
    if (ci < 1200)      { p = p3; W = 80; lvl = 0; il0 = ci * 16;          base = 0;     }
    else if (ci < 1500) { p = p4; W = 40; lvl = 1; il0 = (ci - 1200) * 16; base = 19200; }
    else                { p = p5; W = 20; lvl = 2; il0 = (ci - 1500) * 16; base = 24000; }
    float stride = (float)(8 << lvl);

    __shared__ float raw_s[4][16 * 85];   // 4 x 5440 B = 21760 B
    __shared__ float obj_s[4][16];        // fast-sigmoid obj (screening)
    float* raw = raw_s[wave];
    float* obj_sh = obj_s[wave];

    // Stage this wave's 16 anchors (1360 floats = 340 float4, coalesced).
    {
        const float4* src4 = (const float4*)(p + (size_t)b * ((size_t)W * W * 255) +
                                             (size_t)il0 * 85);
        float4* raw4 = (float4*)raw;
#pragma unroll
        for (int k = 0; k < 6; ++k) {
            int idx = lane + k * 64;
            if (idx < 340) raw4[idx] = src4[idx];
        }
    }
    __threadfence_block();   // drain ds_writes: wave-wide LDS visibility

    // Box phase: lanes 0..15, one anchor each, EXACT math, float4 store
    // (16 lanes x 16 B = 256 B contiguous).
    if (lane < 16) {
        int a = lane;
        int il = il0 + a;
        int y = il / (W * 3);
        int t = il - y * (W * 3);
        int x = t / 3;
        int an = t - x * 3;
        const float* q = &raw[a * 85];
        float cx = (sigmoidf_(q[0]) + (float)x) * stride;
        float cy = (sigmoidf_(q[1]) + (float)y) * stride;
        float bw = expf(q[2]) * c_anch[lvl * 3 + an][0];
        float bh = expf(q[3]) * c_anch[lvl * 3 + an][1];
        float4 bo = {cx - bw * 0.5f, cy - bh * 0.5f,
                     cx + bw * 0.5f, cy + bh * 0.5f};
        *(float4*)(boxes + ((size_t)b * N_ANCH + base + il) * 4) = bo;
        obj_sh[a] = fast_sigmoid_(q[4]);   // screening obj
    }
    __threadfence_block();   // obj_sh visible wave-wide

    // Score phase: lane -> class; 2 iterations (it1: lanes 0..15 -> c 64..79).
    // Each lane packs 16 anchors' u8 bins into one uint4 store.
    size_t rowbase = (size_t)b * NUM_CLASSES * N_ANCH + (size_t)(base + il0);
#pragma unroll
    for (int it = 0; it < 2; ++it) {
        int c = it * 64 + lane;
        if (c < NUM_CLASSES) {
            unsigned int w[4];
#pragma unroll
            for (int g = 0; g < 4; ++g) {
                unsigned int acc = 0;
#pragma unroll
                for (int a4 = 0; a4 < 4; ++a4) {
                    int a = g * 4 + a4;
                    float s = obj_sh[a] * fast_sigmoid_(raw[a * 85 + 5 + c]);
                    acc |= score_u8_(s) << (8 * a4);
                }
                w[g] = acc;
            }
            uint4 v = {w[0], w[1], w[2], w[3]};
            *(uint4*)(score_u8 + rowbase + (size_t)c * N_ANCH) = v;
        }
    }
}

// ---- F2a: per (image,class) top-128 selection over u8 screening bins ----
// Histogram cutoff on fast bins (with -1 margin => provable superset of the
// exact top-128), then EXACT score recompute from raw logits.
__global__ void __launch_bounds__(256) select_topk_u8_kernel(
    const unsigned char* __restrict__ score_u8,
    const float* __restrict__ p3, const float* __restrict__ p4,
    const float* __restrict__ p5,
    unsigned long long* __restrict__ topsel) {
    int bc = blockIdx.x;
    int b = bc / NUM_CLASSES;
    int c = bc - b * NUM_CLASSES;
    int tid = threadIdx.x;
    int wave = tid >> 6;
    const uint4* sc = (const uint4*)(score_u8 + (size_t)bc * N_ANCH);

    __shared__ unsigned int hist[4][256];         // per-wave copies, 4 KB
    __shared__ unsigned long long sel[CAPB];      // 8 KB
    __shared__ unsigned int s_cnt;
    __shared__ int s_cut;

#pragma unroll
    for (int wv = 0; wv < 4; ++wv) hist[wv][tid & 255] = 0u;
    if (tid == 0) s_cnt = 0u;
    __syncthreads();

    // Pass 1: histogram of u8 bins (coalesced 16B reads, 16 u8/load)
    unsigned int* myhist = hist[wave];
    for (int i = tid; i < N_ANCH / 16; i += 256) {
        uint4 v = sc[i];
        unsigned int ww[4] = {v.x, v.y, v.z, v.w};
#pragma unroll
        for (int k = 0; k < 16; ++k) {
            unsigned int bin = (ww[k >> 2] >> ((k & 3) * 8)) & 0xFFu;
            if (bin) atomicAdd(&myhist[bin], 1u);
        }
    }
    __syncthreads();

    // merge per-wave copies into hist[0][*]
    {
        unsigned int m = hist[0][tid] + hist[1][tid] + hist[2][tid] + hist[3][tid];
        hist[0][tid] = m;
    }
    __syncthreads();

    if (tid == 0) {
        unsigned int tot = 0; int cut = 0;
        for (int t = 255; t >= 1; --t) {
            tot += hist[0][t];
            if (tot >= NMS_TOPK_) { cut = t; break; }
        }
        s_cut = cut;
    }
    __syncthreads();
    // -1 margin: fast-vs-exact error (<2 u16-ulps in score, << 1 bin) can
    // shift a true top-128 item down by at most one bin.
    int coll = s_cut - 1;
    if (coll < 1) coll = 1;

    // Pass 2: collect candidate indices at/above collection bin
    for (int i = tid; i < N_ANCH / 16; i += 256) {
        uint4 v = sc[i];
        unsigned int ww[4] = {v.x, v.y, v.z, v.w};
#pragma unroll
        for (int k = 0; k < 16; ++k) {
            unsigned int bin = (ww[k >> 2] >> ((k & 3) * 8)) & 0xFFu;
            if ((int)bin >= coll) {
                unsigned int pos = atomicAdd(&s_cnt, 1u);
                if (pos < CAPB) sel[pos] = (unsigned long long)(i * 16 + k);
            }
        }
    }
    __syncthreads();

    unsigned int M = s_cnt;
    if (M > CAPB) M = CAPB;

    // EXACT score recompute (bitwise identical formula to reference)
    for (unsigned int t = tid; t < M; t += 256) {
        unsigned int idx = (unsigned int)sel[t];
        const float* q;
        if (idx < 19200u)      q = p3 + (size_t)b * 1632000 + (size_t)idx * 85;
        else if (idx < 24000u) q = p4 + (size_t)b * 408000 + (size_t)(idx - 19200u) * 85;
        else                   q = p5 + (size_t)b * 102000 + (size_t)(idx - 24000u) * 85;
        float s = sigmoidf_(q[4]) * sigmoidf_(q[5 + c]);
        sel[t] = (s > SCORE_THR_)
                     ? (((unsigned long long)__float_as_uint(s) << 32) |
                        (unsigned long long)(~idx))
                     : 0ull;
    }
    __syncthreads();

    unsigned int P2 = 1;
    while (P2 < M) P2 <<= 1;
    if (P2 < 2) P2 = 2;
    for (unsigned int k = M + tid; k < P2; k += 256) sel[k] = 0ull;
    __syncthreads();

    // 256-thread bitonic sort, desc order
    for (unsigned int k = 2; k <= P2; k <<= 1) {
        for (unsigned int j = k >> 1; j > 0; j >>= 1) {
            for (unsigned int t = tid; t < (int)P2; t += 256) {
                unsigned int ixj = (unsigned int)t ^ j;
                if (ixj > (unsigned int)t) {
                    unsigned long long a0 = sel[t], b0 = sel[ixj];
                    bool desc = (((unsigned int)t & k) == 0);
                    if (desc ? (a0 < b0) : (a0 > b0)) { sel[t] = b0; sel[ixj] = a0; }
                }
            }
            __syncthreads();
        }
    }

    unsigned long long* dst = topsel + (size_t)bc * NMS_TOPK_;
    if (tid < NMS_TOPK_) dst[tid] = ((unsigned int)tid < M) ? sel[tid] : 0ull;
}

// ---- F2b: wave-synchronous greedy NMS per (image,class), 1 wave/block ----
__global__ void __launch_bounds__(64) nms_kernel(
    const unsigned long long* __restrict__ topsel,
    const float* __restrict__ boxes,
    float* __restrict__ cls_score, float* __restrict__ cls_box) {
    int bc = blockIdx.x;
    int b = bc / NUM_CLASSES;
    unsigned int lane = threadIdx.x;

    __shared__ float bx[NMS_TOPK_][8];   // box(4) + pad; float4-aligned rows

    const unsigned long long* src = topsel + (size_t)bc * NMS_TOPK_;
    unsigned long long e0 = src[lane];
    unsigned long long e1 = src[64 + lane];

    bool k0 = (e0 != 0ull);
    bool k1 = (e1 != 0ull);

    float x00 = 0, y00 = 0, x01 = 0, y01 = 0, a0 = 0, sv0 = 0;
    float x10 = 0, y10 = 0, x11 = 0, y11 = 0, a1 = 0, sv1 = 0;
    if (k0) {
        unsigned int idx = ~((unsigned int)(e0 & 0xFFFFFFFFull));
        float4 bp = *(const float4*)(boxes + ((size_t)b * N_ANCH + idx) * 4);
        x00 = bp.x; y00 = bp.y; x01 = bp.z; y01 = bp.w;
        sv0 = __uint_as_float((unsigned int)(e0 >> 32));
        a0 = (x01 - x00) * (y01 - y00);
    }
    if (k1) {
        unsigned int idx = ~((unsigned int)(e1 & 0xFFFFFFFFull));
        float4 bp = *(const float4*)(boxes + ((size_t)b * N_ANCH + idx) * 4);
        x10 = bp.x; y10 = bp.y; x11 = bp.z; y11 = bp.w;
        sv1 = __uint_as_float((unsigned int)(e1 >> 32));
        a1 = (x11 - x10) * (y11 - y10);
    }
    {
        float4 v0 = {x00, y00, x01, y01};
        float4 v1 = {x10, y10, x11, y11};
        *(float4*)&bx[lane][0] = v0;
        *(float4*)&bx[64 + lane][0] = v1;
    }
    __syncthreads();

    unsigned long long km0 = __ballot(k0);
    unsigned long long km1 = __ballot(k1);
    for (unsigned int i = 0; i < NMS_TOPK_; ++i) {
        bool ki = ((((i < 64) ? km0 : km1) >> (i & 63)) & 1ull) != 0ull;
        if (ki) {
            float4 rb = *(const float4*)&bx[i][0];
            float ra = (rb.z - rb.x) * (rb.w - rb.y);
            if (k0 && lane > i) {
                float lx = fmaxf(rb.x, x00), ly = fmaxf(rb.y, y00);
                float rx = fminf(rb.z, x01), ry = fminf(rb.w, y01);
                float w = fmaxf(rx - lx, 0.f), h = fmaxf(ry - ly, 0.f);
                float inter = w * h;
                float iou = inter / (ra + a0 - inter + 1e-9f);
                if (iou > IOU_THR_) k0 = false;
            }
            if (k1 && (64 + lane) > i) {
                float lx = fmaxf(rb.x, x10), ly = fmaxf(rb.y, y10);
                float rx = fminf(rb.z, x11), ry = fminf(rb.w, y11);
                float w = fmaxf(rx - lx, 0.f), h = fmaxf(ry - ly, 0.f);
                float inter = w * h;
                float iou = inter / (ra + a1 - inter + 1e-9f);
                if (iou > IOU_THR_) k1 = false;
            }
            km0 = __ballot(k0);
            km1 = __ballot(k1);
        }
    }

    // Parallel compaction straight from registers
    float* scd = cls_score + (size_t)bc * MAX_OUT_;
    float* bod = cls_box + (size_t)bc * (MAX_OUT_ * 4);
    int n0 = __popcll(km0);
    int n = n0 + __popcll(km1);
    if (k0) {
        int pos = __popcll(km0 & ((1ull << lane) - 1ull));
        if (pos < MAX_OUT_) {
            scd[pos] = sv0;
            bod[pos * 4 + 0] = x00; bod[pos * 4 + 1] = y00;
            bod[pos * 4 + 2] = x01; bod[pos * 4 + 3] = y01;
        }
    }
    if (k1) {
        int pos = n0 + __popcll(km1 & ((1ull << lane) - 1ull));
        if (pos < MAX_OUT_) {
            scd[pos] = sv1;
            bod[pos * 4 + 0] = x10; bod[pos * 4 + 1] = y10;
            bod[pos * 4 + 2] = x11; bod[pos * 4 + 3] = y11;
        }
    }
    int start = n < MAX_OUT_ ? n : MAX_OUT_;
    for (int p2 = start + (int)lane; p2 < MAX_OUT_; p2 += 64) {
        scd[p2] = -1.0f;
        bod[p2 * 4 + 0] = 0.f; bod[p2 * 4 + 1] = 0.f;
        bod[p2 * 4 + 2] = 0.f; bod[p2 * 4 + 3] = 0.f;
    }
}

// ---- F3: per-image final top-100 via histogram cutoff ----
__global__ void __launch_bounds__(256) final_fast_kernel(
    const float* __restrict__ cls_score, const float* __restrict__ cls_box,
    float* __restrict__ out) {
    int b = blockIdx.x;
    int tid = threadIdx.x;
    const int NC = NUM_CLASSES * MAX_OUT_;  // 8000
    const float* sc = cls_score + (size_t)b * NC;

    __shared__ unsigned int hist[NBINS];
    __shared__ unsigned int segsum[256];
    __shared__ unsigned long long keys[CAPC];
    __shared__ unsigned int s_cnt, s_tot;
    __shared__ int s_cut;

    for (int k = tid; k < NBINS; k += 256) hist[k] = 0u;
    if (tid == 0) s_cnt = 0u;
    __syncthreads();

    for (int k = tid; k < NC; k += 256) {
        float s = sc[k];
        if (s > 0.0f) atomicAdd(&hist[score_bin(__float_as_uint(s))], 1u);
    }
    __syncthreads();

    unsigned int ss = 0;
    for (int k = 0; k < 8; ++k) ss += hist[tid * 8 + k];
    segsum[tid] = ss;
    __syncthreads();
    if (tid == 0) {
        unsigned int total = 0;
        for (int t = 0; t < 256; ++t) total += segsum[t];
        s_tot = total;
        unsigned int tot = 0; int cut = 0; int t = 255;
        for (; t >= 0; --t) {
            if (tot + segsum[t] >= MAX_OUT_) break;
            tot += segsum[t];
        }
        if (t >= 0) {
            int j = 7;
            for (; j >= 0; --j) { tot += hist[t * 8 + j]; if (tot >= MAX_OUT_) break; }
            if (j < 0) j = 0;
            cut = t * 8 + j;
        }
        s_cut = cut;
    }
    __syncthreads();
    unsigned int cutoff = (unsigned int)s_cut;

    for (int k = tid; k < NC; k += 256) {
        float s = sc[k];
        if (s > 0.0f && score_bin(__float_as_uint(s)) >= cutoff) {
            unsigned int pos = atomicAdd(&s_cnt, 1u);
            if (pos < CAPC) {
                keys[pos] = ((unsigned long long)__float_as_uint(s) << 32) |
                            (unsigned long long)(~(unsigned int)k);
            }
        }
    }
    __syncthreads();

    unsigned int M = s_cnt;
    if (M > CAPC) M = CAPC;
    unsigned int P2 = 1;
    while (P2 < M) P2 <<= 1;
    if (P2 < 2) P2 = 2;
    for (unsigned int k = M + tid; k < P2; k += 256) keys[k] = 0ull;
    __syncthreads();

    for (unsigned int k = 2; k <= P2; k <<= 1) {
        for (unsigned int j = k >> 1; j > 0; j >>= 1) {
            for (unsigned int t = (unsigned int)tid; t < P2; t += 256) {
                unsigned int ixj = t ^ j;
                if (ixj > t) {
                    unsigned long long a0 = keys[t], b0 = keys[ixj];
                    bool desc = ((t & k) == 0);
                    if (desc ? (a0 < b0) : (a0 > b0)) { keys[t] = b0; keys[ixj] = a0; }
                }
            }
            __syncthreads();
        }
    }

    float* ob = out;                              // boxes  16*100*4
    float* os = out + B_IMG * MAX_OUT_ * 4;       // scores 16*100
    float* oc = os + B_IMG * MAX_OUT_;            // cls    16*100
    float* on = oc + B_IMG * MAX_OUT_;            // n_valid 16

    unsigned int K = M < MAX_OUT_ ? M : MAX_OUT_;
    if (tid < MAX_OUT_) {
        if ((unsigned int)tid < K) {
            unsigned long long kk = keys[tid];
            unsigned int flat = ~((unsigned int)(kk & 0xFFFFFFFFull));
            float sv = __uint_as_float((unsigned int)(kk >> 32));
            const float* bp = cls_box + ((size_t)b * NC + flat) * 4;
            os[b * MAX_OUT_ + tid] = sv;
            oc[b * MAX_OUT_ + tid] = (float)(flat / MAX_OUT_);
            ob[(b * MAX_OUT_ + tid) * 4 + 0] = bp[0];
            ob[(b * MAX_OUT_ + tid) * 4 + 1] = bp[1];
            ob[(b * MAX_OUT_ + tid) * 4 + 2] = bp[2];
            ob[(b * MAX_OUT_ + tid) * 4 + 3] = bp[3];
        } else {
            os[b * MAX_OUT_ + tid] = 0.0f;
            oc[b * MAX_OUT_ + tid] = 0.0f;
            ob[(b * MAX_OUT_ + tid) * 4 + 0] = 0.0f;
            ob[(b * MAX_OUT_ + tid) * 4 + 1] = 0.0f;
            ob[(b * MAX_OUT_ + tid) * 4 + 2] = 0.0f;
            ob[(b * MAX_OUT_ + tid) * 4 + 3] = 0.0f;
        }
    }
    if (tid == 0) {
        unsigned int nv = s_tot < MAX_OUT_ ? s_tot : MAX_OUT_;
        on[b] = (float)nv;
    }
}

// ============================================================================
// FALLBACK PATH (round-1, known-correct) — used when ws_size is too small
// ============================================================================

__global__ void __launch_bounds__(256) decode_kernel(
    const float* __restrict__ p3, const float* __restrict__ p4,
    const float* __restrict__ p5, float* __restrict__ boxes,
    float* __restrict__ obj) {
    int gid = blockIdx.x * blockDim.x + threadIdx.x;
    if (gid >= B_IMG * N_ANCH) return;
    int b = gid / N_ANCH;
    int i = gid - b * N_ANCH;
    const float* p; int W, il, lvl; float stride;
    if (i < 19200)      { p = p3; W = 80; il = i;         lvl = 0; stride = 8.f;  }
    else if (i < 24000) { p = p4; W = 40; il = i - 19200; lvl = 1; stride = 16.f; }
    else                { p = p5; W = 20; il = i - 24000; lvl = 2; stride = 32.f; }
    int y = il / (W * 3);
    int t = il - y * W * 3;
    int x = t / 3;
    int a = t - x * 3;
    const float* q = p + ((((size_t)b * W + y) * W + x) * 255 + a * 85);
    float cx = (sigmoidf_(q[0]) + (float)x) * stride;
    float cy = (sigmoidf_(q[1]) + (float)y) * stride;
    float bw = expf(q[2]) * c_anch[lvl * 3 + a][0];
    float bh = expf(q[3]) * c_anch[lvl * 3 + a][1];
    float* bo = boxes + (size_t)gid * 4;
    bo[0] = cx - bw * 0.5f; bo[1] = cy - bh * 0.5f;
    bo[2] = cx + bw * 0.5f; bo[3] = cy + bh * 0.5f;
    obj[gid] = sigmoidf_(q[4]);
}

__device__ __forceinline__ float cand_score(
    const float* __restrict__ p3, const float* __restrict__ p4,
    const float* __restrict__ p5, const float* __restrict__ obj,
    int b, int c, int i) {
    const float* p; int W, il;
    if (i < 19200)      { p = p3; W = 80; il = i;         }
    else if (i < 24000) { p = p4; W = 40; il = i - 19200; }
    else                { p = p5; W = 20; il = i - 24000; }
    int y = il / (W * 3);
    int t = il - y * W * 3;
    int x = t / 3;
    int a = t - x * 3;
    float cl = p[(((size_t)b * W + y) * W + x) * 255 + a * 85 + 5 + c];
    return obj[b * N_ANCH + i] * sigmoidf_(cl);
}

__global__ void __launch_bounds__(256) topk_nms_kernel(
    const float* __restrict__ p3, const float* __restrict__ p4,
    const float* __restrict__ p5, const float* __restrict__ boxes,
    const float* __restrict__ obj, float* __restrict__ cls_score,
    float* __restrict__ cls_box) {
    int b = blockIdx.x / NUM_CLASSES;
    int c = blockIdx.x % NUM_CLASSES;
    int tid = threadIdx.x;

    __shared__ unsigned int hist[NBINS];
    __shared__ unsigned long long keys[CAP];
    __shared__ unsigned int s_cnt, s_cutoff;
    __shared__ float bx[NMS_TOPK_][5];
    __shared__ float bs[NMS_TOPK_];
    __shared__ int keep[NMS_TOPK_];

    for (int k = tid; k < NBINS; k += 256) hist[k] = 0u;
    if (tid == 0) s_cnt = 0u;
    __syncthreads();

    for (int i = tid; i < N_ANCH; i += 256) {
        float s = cand_score(p3, p4, p5, obj, b, c, i);
        if (s > SCORE_THR_) atomicAdd(&hist[score_bin(__float_as_uint(s))], 1u);
    }
    __syncthreads();

    if (tid == 0) {
        unsigned int total = 0;
        int cut = 0;
        for (int k = NBINS - 1; k >= 0; --k) {
            total += hist[k];
            if (total >= NMS_TOPK_) { cut = k; break; }
        }
        s_cutoff = (unsigned int)cut;
    }
    __syncthreads();
    unsigned int cutoff = s_cutoff;

    for (int i = tid; i < N_ANCH; i += 256) {
        float s = cand_score(p3, p4, p5, obj, b, c, i);
        if (s > SCORE_THR_) {
            unsigned int bits = __float_as_uint(s);
            if (score_bin(bits) >= cutoff) {
                unsigned int pos = atomicAdd(&s_cnt, 1u);
                if (pos < CAP) {
                    keys[pos] = ((unsigned long long)bits << 32) |
                                (unsigned long long)(~(unsigned int)i);
                }
            }
        }
    }
    __syncthreads();

    unsigned int M = s_cnt;
    if (M > CAP) M = CAP;
    unsigned int P2 = 1;
    while (P2 < M) P2 <<= 1;
    if (P2 < 2) P2 = 2;
    for (unsigned int k = M + tid; k < P2; k += 256) keys[k] = 0ull;
    __syncthreads();

    for (unsigned int k = 2; k <= P2; k <<= 1) {
        for (unsigned int j = k >> 1; j > 0; j >>= 1) {
            for (unsigned int t = tid; t < P2; t += 256) {
                unsigned int ixj = t ^ j;
                if (ixj > t) {
                    unsigned long long a0 = keys[t], b0 = keys[ixj];
                    bool desc = ((t & k) == 0);
                    if (desc ? (a0 < b0) : (a0 > b0)) { keys[t] = b0; keys[ixj] = a0; }
                }
            }
            __syncthreads();
        }
    }

    unsigned int K = M < NMS_TOPK_ ? M : NMS_TOPK_;
    if (tid < (int)K) {
        unsigned long long kk = keys[tid];
        unsigned int idx = ~((unsigned int)(kk & 0xFFFFFFFFull));
        const float* bp = boxes + ((size_t)b * N_ANCH + idx) * 4;
        bx[tid][0] = bp[0]; bx[tid][1] = bp[1];
        bx[tid][2] = bp[2]; bx[tid][3] = bp[3];
        bs[tid] = __uint_as_float((unsigned int)(kk >> 32));
        keep[tid] = 1;
    }
    __syncthreads();

    for (unsigned int i = 0; i < K; ++i) {
        if (keep[i]) {
            unsigned int t = (unsigned int)tid;
            if (t > i && t < K && keep[t]) {
                float ax0 = bx[i][0], ay0 = bx[i][1], ax1 = bx[i][2], ay1 = bx[i][3];
                float cx0 = bx[t][0], cy0 = bx[t][1], cx1 = bx[t][2], cy1 = bx[t][3];
                float areaA = (ax1 - ax0) * (ay1 - ay0);
                float areaB = (cx1 - cx0) * (cy1 - cy0);
                float lx = fmaxf(ax0, cx0), ly = fmaxf(ay0, cy0);
                float rx = fminf(ax1, cx1), ry = fminf(ay1, cy1);
                float w = rx - lx; if (w < 0.f) w = 0.f;
                float h = ry - ly; if (h < 0.f) h = 0.f;
                float inter = w * h;
                float iou = inter / (areaA + areaB - inter + 1e-9f);
                if (iou > IOU_THR_) keep[t] = 0;
            }
        }
        __syncthreads();
    }

    if (tid == 0) {
        float* scd = cls_score + ((size_t)b * NUM_CLASSES + c) * MAX_OUT_;
        float* bod = cls_box + ((size_t)b * NUM_CLASSES + c) * MAX_OUT_ * 4;
        int out_n = 0;
        for (unsigned int t2 = 0; t2 < K && out_n < MAX_OUT_; ++t2) {
            if (keep[t2]) {
                scd[out_n] = bs[t2];
                bod[out_n * 4 + 0] = bx[t2][0];
                bod[out_n * 4 + 1] = bx[t2][1];
                bod[out_n * 4 + 2] = bx[t2][2];
                bod[out_n * 4 + 3] = bx[t2][3];
                out_n++;
            }
        }
        for (; out_n < MAX_OUT_; ++out_n) {
            scd[out_n] = -1.0f;
            bod[out_n * 4 + 0] = 0.f; bod[out_n * 4 + 1] = 0.f;
            bod[out_n * 4 + 2] = 0.f; bod[out_n * 4 + 3] = 0.f;
        }
    }
}

extern "C" void kernel_launch(void* const* d_in, const int* in_sizes, int n_in,
                              void* d_out, int out_size, void* d_ws, size_t ws_size,
                              hipStream_t stream) {
    const float* p3 = (const float*)d_in[0];
    const float* p4 = (const float*)d_in[1];
    const float* p5 = (const float*)d_in[2];

    const size_t boxesB  = (size_t)B_IMG * N_ANCH * 4 * sizeof(float);          // 6,451,200
    const size_t clsSB   = (size_t)B_IMG * NUM_CLASSES * MAX_OUT_ * sizeof(float); // 512,000
    const size_t clsBB   = clsSB * 4;                                            // 2,048,000
    const size_t topselB = (size_t)B_IMG * NUM_CLASSES * NMS_TOPK_ * 8;          // 1,310,720
    const size_t scoreUB = (size_t)B_IMG * NUM_CLASSES * N_ANCH;                 // 32,256,000 (u8)
    const size_t need_new = boxesB + clsSB + clsBB + topselB + scoreUB;          // ~42.6 MB

    char* base = (char*)d_ws;

    if (ws_size >= need_new) {
        float* boxes     = (float*)base;
        float* cls_score = (float*)(base + boxesB);
        float* cls_box   = (float*)(base + boxesB + clsSB);
        unsigned long long* topsel =
            (unsigned long long*)(base + boxesB + clsSB + clsBB);
        unsigned char* score_u8 =
            (unsigned char*)(base + boxesB + clsSB + clsBB + topselB);

        decode_wave_kernel<<<(B_IMG * CHUNKS_PER_IMG) / 4, 256, 0, stream>>>(
            p3, p4, p5, boxes, score_u8);
        select_topk_u8_kernel<<<B_IMG * NUM_CLASSES, 256, 0, stream>>>(
            score_u8, p3, p4, p5, topsel);
        nms_kernel<<<B_IMG * NUM_CLASSES, 64, 0, stream>>>(
            topsel, boxes, cls_score, cls_box);
        final_fast_kernel<<<B_IMG, 256, 0, stream>>>(cls_score, cls_box, (float*)d_out);
    } else {
        float* boxes = (float*)base;
        float* obj = boxes + (size_t)B_IMG * N_ANCH * 4;
        float* cls_score = obj + (size_t)B_IMG * N_ANCH;
        float* cls_box = cls_score + (size_t)B_IMG * NUM_CLASSES * MAX_OUT_;

        int tot = B_IMG * N_ANCH;
        decode_kernel<<<(tot + 255) / 256, 256, 0, stream>>>(p3, p4, p5, boxes, obj);
        topk_nms_kernel<<<B_IMG * NUM_CLASSES, 256, 0, stream>>>(
            p3, p4, p5, boxes, obj, cls_score, cls_box);
        final_fast_kernel<<<B_IMG, 256, 0, stream>>>(cls_score, cls_box, (float*)d_out);
    }
}

// Round 6
// 295.231 us; speedup vs baseline: 1.1288x; 1.0097x over previous
//
#include <hip/hip_runtime.h>
#include <stdint.h>

#define NUM_CLASSES 80
#define N_ANCH 25200
#define B_IMG 16
#define NMS_TOPK_ 128
#define MAX_OUT_ 100
#define SCORE_THR_ 0.25f
#define IOU_THR_ 0.45f
#define NBINS 2048      // fallback path histogram bins
#define CAP 2048        // fallback path capacity
#define CAPB 1024       // u8-select candidate capacity
#define CAPC 256        // stage-C capacity
#define U8_BASE 0x3E7Eu // 2-ulp margin below u16(0.25)=0x3E80 (screening only)
#define TILES_PER_IMG 394   // p3:300 + p4:75 + p5:19 (last p5 tile = 48 anchors)

__constant__ float c_anch[9][2] = {
    {10.f, 13.f}, {16.f, 30.f}, {33.f, 23.f},
    {30.f, 61.f}, {62.f, 45.f}, {59.f, 119.f},
    {116.f, 90.f}, {156.f, 198.f}, {373.f, 326.f}};

// Exact sigmoid — used for box decode and for the exact re-scoring of
// selected candidates (must match the jax reference bitwise-closely).
__device__ __forceinline__ float sigmoidf_(float x) {
    return 1.0f / (1.0f + expf(-x));
}

// Fast screening sigmoid. |err| <= ~3e-7. ONLY feeds the u8 screening
// tensor; never reaches the output.
__device__ __forceinline__ float fast_sigmoid_(float x) {
    float t = __expf(-x);
    return __fdividef(1.0f, 1.0f + t);
}

// Map score to u8 screening bin. 0 = below ~0.2485 (margin), 1..255 above.
__device__ __forceinline__ unsigned int score_u8_(float s) {
    unsigned int u = __float_as_uint(s) >> 16;
    int bin = (int)u - (int)U8_BASE;
    if (bin < 0) bin = 0;
    if (bin > 255) bin = 255;
    return (unsigned int)bin;
}

__device__ __forceinline__ unsigned int score_bin(unsigned int bits) {
    // fallback path: scores in (0.25, 1.0): bits in (0x3E800000, 0x3F800000)
    unsigned int bin = (bits - 0x3E800000u) >> 13;
    if (bin >= NBINS) bin = NBINS - 1;
    return bin;
}

// ============================================================================
// FAST PATH (u8 screening tensor, anchor-per-lane decode, exact re-score)
// ============================================================================

// ---- F1: tile decode. Block = 64-anchor tile; lane = anchor; each wave
// iterates 20 classes. Score stores are 64B-contiguous; obj lives in a
// register; single block barrier.
__global__ void __launch_bounds__(256) decode_tile_kernel(
    const float* __restrict__ p3, const float* __restrict__ p4,
    const float* __restrict__ p5, float* __restrict__ boxes,
    unsigned char* __restrict__ score_u8) {
    int blk = blockIdx.x;
    int b = blk / TILES_PER_IMG;
    int tile = blk - b * TILES_PER_IMG;
    const float* p; int W, lvl, il0, base, ta;
    if (tile < 300)      { p = p3; W = 80; lvl = 0; il0 = tile * 64;         base = 0;     ta = 64; }
    else if (tile < 375) { p = p4; W = 40; lvl = 1; il0 = (tile - 300) * 64; base = 19200; ta = 64; }
    else                 { p = p5; W = 20; lvl = 2; il0 = (tile - 375) * 64; base = 24000;
                           ta = (tile == 393) ? 48 : 64; }
    float stride = (float)(8 << lvl);

    __shared__ float raw[64 * 85];   // 21760 B
    int tid = threadIdx.x;

    // Stage tile (ta*85 floats, coalesced float4)
    {
        const float4* src4 = (const float4*)(p + (size_t)b * ((size_t)W * W * 255) +
                                             (size_t)il0 * 85);
        float4* raw4 = (float4*)raw;
        int n4 = ta * 85 / 4;   // 1360 or 1020
        for (int k = tid; k < n4; k += 256) raw4[k] = src4[k];
    }
    __syncthreads();

    int wave = tid >> 6;
    int lane = tid & 63;

    // Box phase: each wave decodes 16 anchors (lane<16), EXACT math,
    // float4 store (16 x 16 B = 256 B contiguous per wave).
    if (lane < 16) {
        int a = wave * 16 + lane;
        if (a < ta) {
            int il = il0 + a;
            int y = il / (W * 3);
            int t = il - y * (W * 3);
            int x = t / 3;
            int an = t - x * 3;
            const float* q = &raw[a * 85];
            float cx = (sigmoidf_(q[0]) + (float)x) * stride;
            float cy = (sigmoidf_(q[1]) + (float)y) * stride;
            float bw = expf(q[2]) * c_anch[lvl * 3 + an][0];
            float bh = expf(q[3]) * c_anch[lvl * 3 + an][1];
            float4 bo = {cx - bw * 0.5f, cy - bh * 0.5f,
                         cx + bw * 0.5f, cy + bh * 0.5f};
            *(float4*)(boxes + ((size_t)b * N_ANCH + base + il) * 4) = bo;
        }
    }

    // Score phase: lane = anchor; wave w covers classes 20w..20w+19.
    // Per class-iter: 1 LDS read (bank-conflict-free: stride 85, gcd(85,32)=1),
    // 1 fast sigmoid, 1 byte store into a 64B-contiguous run.
    if (lane < ta) {
        const float* q = &raw[lane * 85];
        float obj = fast_sigmoid_(q[4]);          // register; screening only
        size_t sb = (size_t)b * NUM_CLASSES * N_ANCH + (size_t)(base + il0 + lane);
#pragma unroll
        for (int it = 0; it < 20; ++it) {
            int c = wave * 20 + it;
            float s = obj * fast_sigmoid_(q[5 + c]);
            score_u8[sb + (size_t)c * N_ANCH] = (unsigned char)score_u8_(s);
        }
    }
}

// ---- F2a: per (image,class) top-128 selection over u8 screening bins ----
// Histogram cutoff on fast bins (with -1 margin => provable superset of the
// exact top-128), then EXACT score recompute from raw logits.
__global__ void __launch_bounds__(256) select_topk_u8_kernel(
    const unsigned char* __restrict__ score_u8,
    const float* __restrict__ p3, const float* __restrict__ p4,
    const float* __restrict__ p5,
    unsigned long long* __restrict__ topsel) {
    int bc = blockIdx.x;
    int b = bc / NUM_CLASSES;
    int c = bc - b * NUM_CLASSES;
    int tid = threadIdx.x;
    int wave = tid >> 6;
    const uint4* sc = (const uint4*)(score_u8 + (size_t)bc * N_ANCH);

    __shared__ unsigned int hist[4][256];         // per-wave copies, 4 KB
    __shared__ unsigned long long sel[CAPB];      // 8 KB
    __shared__ unsigned int s_cnt;
    __shared__ int s_cut;

#pragma unroll
    for (int wv = 0; wv < 4; ++wv) hist[wv][tid & 255] = 0u;
    if (tid == 0) s_cnt = 0u;
    __syncthreads();

    // Pass 1: histogram of u8 bins (coalesced 16B reads, 16 u8/load)
    unsigned int* myhist = hist[wave];
    for (int i = tid; i < N_ANCH / 16; i += 256) {
        uint4 v = sc[i];
        unsigned int ww[4] = {v.x, v.y, v.z, v.w};
#pragma unroll
        for (int k = 0; k < 16; ++k) {
            unsigned int bin = (ww[k >> 2] >> ((k & 3) * 8)) & 0xFFu;
            if (bin) atomicAdd(&myhist[bin], 1u);
        }
    }
    __syncthreads();

    // merge per-wave copies into hist[0][*]
    {
        unsigned int m = hist[0][tid] + hist[1][tid] + hist[2][tid] + hist[3][tid];
        hist[0][tid] = m;
    }
    __syncthreads();

    if (tid == 0) {
        unsigned int tot = 0; int cut = 0;
        for (int t = 255; t >= 1; --t) {
            tot += hist[0][t];
            if (tot >= NMS_TOPK_) { cut = t; break; }
        }
        s_cut = cut;
    }
    __syncthreads();
    // -1 margin: fast-vs-exact error (<2 u16-ulps in score, << 1 bin) can
    // shift a true top-128 item down by at most one bin.
    int coll = s_cut - 1;
    if (coll < 1) coll = 1;

    // Pass 2: collect candidate indices at/above collection bin
    for (int i = tid; i < N_ANCH / 16; i += 256) {
        uint4 v = sc[i];
        unsigned int ww[4] = {v.x, v.y, v.z, v.w};
#pragma unroll
        for (int k = 0; k < 16; ++k) {
            unsigned int bin = (ww[k >> 2] >> ((k & 3) * 8)) & 0xFFu;
            if ((int)bin >= coll) {
                unsigned int pos = atomicAdd(&s_cnt, 1u);
                if (pos < CAPB) sel[pos] = (unsigned long long)(i * 16 + k);
            }
        }
    }
    __syncthreads();

    unsigned int M = s_cnt;
    if (M > CAPB) M = CAPB;

    // EXACT score recompute (bitwise identical formula to reference)
    for (unsigned int t = tid; t < M; t += 256) {
        unsigned int idx = (unsigned int)sel[t];
        const float* q;
        if (idx < 19200u)      q = p3 + (size_t)b * 1632000 + (size_t)idx * 85;
        else if (idx < 24000u) q = p4 + (size_t)b * 408000 + (size_t)(idx - 19200u) * 85;
        else                   q = p5 + (size_t)b * 102000 + (size_t)(idx - 24000u) * 85;
        float s = sigmoidf_(q[4]) * sigmoidf_(q[5 + c]);
        sel[t] = (s > SCORE_THR_)
                     ? (((unsigned long long)__float_as_uint(s) << 32) |
                        (unsigned long long)(~idx))
                     : 0ull;
    }
    __syncthreads();

    unsigned int P2 = 1;
    while (P2 < M) P2 <<= 1;
    if (P2 < 2) P2 = 2;
    for (unsigned int k = M + tid; k < P2; k += 256) sel[k] = 0ull;
    __syncthreads();

    // 256-thread bitonic sort, desc order
    for (unsigned int k = 2; k <= P2; k <<= 1) {
        for (unsigned int j = k >> 1; j > 0; j >>= 1) {
            for (unsigned int t = tid; t < (int)P2; t += 256) {
                unsigned int ixj = (unsigned int)t ^ j;
                if (ixj > (unsigned int)t) {
                    unsigned long long a0 = sel[t], b0 = sel[ixj];
                    bool desc = (((unsigned int)t & k) == 0);
                    if (desc ? (a0 < b0) : (a0 > b0)) { sel[t] = b0; sel[ixj] = a0; }
                }
            }
            __syncthreads();
        }
    }

    unsigned long long* dst = topsel + (size_t)bc * NMS_TOPK_;
    if (tid < NMS_TOPK_) dst[tid] = ((unsigned int)tid < M) ? sel[tid] : 0ull;
}

// ---- F2b: wave-synchronous greedy NMS per (image,class), 1 wave/block ----
__global__ void __launch_bounds__(64) nms_kernel(
    const unsigned long long* __restrict__ topsel,
    const float* __restrict__ boxes,
    float* __restrict__ cls_score, float* __restrict__ cls_box) {
    int bc = blockIdx.x;
    int b = bc / NUM_CLASSES;
    unsigned int lane = threadIdx.x;

    __shared__ float bx[NMS_TOPK_][8];   // box(4) + pad; float4-aligned rows

    const unsigned long long* src = topsel + (size_t)bc * NMS_TOPK_;
    unsigned long long e0 = src[lane];
    unsigned long long e1 = src[64 + lane];

    bool k0 = (e0 != 0ull);
    bool k1 = (e1 != 0ull);

    float x00 = 0, y00 = 0, x01 = 0, y01 = 0, a0 = 0, sv0 = 0;
    float x10 = 0, y10 = 0, x11 = 0, y11 = 0, a1 = 0, sv1 = 0;
    if (k0) {
        unsigned int idx = ~((unsigned int)(e0 & 0xFFFFFFFFull));
        float4 bp = *(const float4*)(boxes + ((size_t)b * N_ANCH + idx) * 4);
        x00 = bp.x; y00 = bp.y; x01 = bp.z; y01 = bp.w;
        sv0 = __uint_as_float((unsigned int)(e0 >> 32));
        a0 = (x01 - x00) * (y01 - y00);
    }
    if (k1) {
        unsigned int idx = ~((unsigned int)(e1 & 0xFFFFFFFFull));
        float4 bp = *(const float4*)(boxes + ((size_t)b * N_ANCH + idx) * 4);
        x10 = bp.x; y10 = bp.y; x11 = bp.z; y11 = bp.w;
        sv1 = __uint_as_float((unsigned int)(e1 >> 32));
        a1 = (x11 - x10) * (y11 - y10);
    }
    {
        float4 v0 = {x00, y00, x01, y01};
        float4 v1 = {x10, y10, x11, y11};
        *(float4*)&bx[lane][0] = v0;
        *(float4*)&bx[64 + lane][0] = v1;
    }
    __syncthreads();

    unsigned long long km0 = __ballot(k0);
    unsigned long long km1 = __ballot(k1);
    for (unsigned int i = 0; i < NMS_TOPK_; ++i) {
        bool ki = ((((i < 64) ? km0 : km1) >> (i & 63)) & 1ull) != 0ull;
        if (ki) {
            float4 rb = *(const float4*)&bx[i][0];
            float ra = (rb.z - rb.x) * (rb.w - rb.y);
            if (k0 && lane > i) {
                float lx = fmaxf(rb.x, x00), ly = fmaxf(rb.y, y00);
                float rx = fminf(rb.z, x01), ry = fminf(rb.w, y01);
                float w = fmaxf(rx - lx, 0.f), h = fmaxf(ry - ly, 0.f);
                float inter = w * h;
                float iou = inter / (ra + a0 - inter + 1e-9f);
                if (iou > IOU_THR_) k0 = false;
            }
            if (k1 && (64 + lane) > i) {
                float lx = fmaxf(rb.x, x10), ly = fmaxf(rb.y, y10);
                float rx = fminf(rb.z, x11), ry = fminf(rb.w, y11);
                float w = fmaxf(rx - lx, 0.f), h = fmaxf(ry - ly, 0.f);
                float inter = w * h;
                float iou = inter / (ra + a1 - inter + 1e-9f);
                if (iou > IOU_THR_) k1 = false;
            }
            km0 = __ballot(k0);
            km1 = __ballot(k1);
        }
    }

    // Parallel compaction straight from registers
    float* scd = cls_score + (size_t)bc * MAX_OUT_;
    float* bod = cls_box + (size_t)bc * (MAX_OUT_ * 4);
    int n0 = __popcll(km0);
    int n = n0 + __popcll(km1);
    if (k0) {
        int pos = __popcll(km0 & ((1ull << lane) - 1ull));
        if (pos < MAX_OUT_) {
            scd[pos] = sv0;
            bod[pos * 4 + 0] = x00; bod[pos * 4 + 1] = y00;
            bod[pos * 4 + 2] = x01; bod[pos * 4 + 3] = y01;
        }
    }
    if (k1) {
        int pos = n0 + __popcll(km1 & ((1ull << lane) - 1ull));
        if (pos < MAX_OUT_) {
            scd[pos] = sv1;
            bod[pos * 4 + 0] = x10; bod[pos * 4 + 1] = y10;
            bod[pos * 4 + 2] = x11; bod[pos * 4 + 3] = y11;
        }
    }
    int start = n < MAX_OUT_ ? n : MAX_OUT_;
    for (int p2 = start + (int)lane; p2 < MAX_OUT_; p2 += 64) {
        scd[p2] = -1.0f;
        bod[p2 * 4 + 0] = 0.f; bod[p2 * 4 + 1] = 0.f;
        bod[p2 * 4 + 2] = 0.f; bod[p2 * 4 + 3] = 0.f;
    }
}

// ---- F3: per-image final top-100 via histogram cutoff ----
__global__ void __launch_bounds__(256) final_fast_kernel(
    const float* __restrict__ cls_score, const float* __restrict__ cls_box,
    float* __restrict__ out) {
    int b = blockIdx.x;
    int tid = threadIdx.x;
    const int NC = NUM_CLASSES * MAX_OUT_;  // 8000
    const float* sc = cls_score + (size_t)b * NC;

    __shared__ unsigned int hist[NBINS];
    __shared__ unsigned int segsum[256];
    __shared__ unsigned long long keys[CAPC];
    __shared__ unsigned int s_cnt, s_tot;
    __shared__ int s_cut;

    for (int k = tid; k < NBINS; k += 256) hist[k] = 0u;
    if (tid == 0) s_cnt = 0u;
    __syncthreads();

    for (int k = tid; k < NC; k += 256) {
        float s = sc[k];
        if (s > 0.0f) atomicAdd(&hist[score_bin(__float_as_uint(s))], 1u);
    }
    __syncthreads();

    unsigned int ss = 0;
    for (int k = 0; k < 8; ++k) ss += hist[tid * 8 + k];
    segsum[tid] = ss;
    __syncthreads();
    if (tid == 0) {
        unsigned int total = 0;
        for (int t = 0; t < 256; ++t) total += segsum[t];
        s_tot = total;
        unsigned int tot = 0; int cut = 0; int t = 255;
        for (; t >= 0; --t) {
            if (tot + segsum[t] >= MAX_OUT_) break;
            tot += segsum[t];
        }
        if (t >= 0) {
            int j = 7;
            for (; j >= 0; --j) { tot += hist[t * 8 + j]; if (tot >= MAX_OUT_) break; }
            if (j < 0) j = 0;
            cut = t * 8 + j;
        }
        s_cut = cut;
    }
    __syncthreads();
    unsigned int cutoff = (unsigned int)s_cut;

    for (int k = tid; k < NC; k += 256) {
        float s = sc[k];
        if (s > 0.0f && score_bin(__float_as_uint(s)) >= cutoff) {
            unsigned int pos = atomicAdd(&s_cnt, 1u);
            if (pos < CAPC) {
                keys[pos] = ((unsigned long long)__float_as_uint(s) << 32) |
                            (unsigned long long)(~(unsigned int)k);
            }
        }
    }
    __syncthreads();

    unsigned int M = s_cnt;
    if (M > CAPC) M = CAPC;
    unsigned int P2 = 1;
    while (P2 < M) P2 <<= 1;
    if (P2 < 2) P2 = 2;
    for (unsigned int k = M + tid; k < P2; k += 256) keys[k] = 0ull;
    __syncthreads();

    for (unsigned int k = 2; k <= P2; k <<= 1) {
        for (unsigned int j = k >> 1; j > 0; j >>= 1) {
            for (unsigned int t = (unsigned int)tid; t < P2; t += 256) {
                unsigned int ixj = t ^ j;
                if (ixj > t) {
                    unsigned long long a0 = keys[t], b0 = keys[ixj];
                    bool desc = ((t & k) == 0);
                    if (desc ? (a0 < b0) : (a0 > b0)) { keys[t] = b0; keys[ixj] = a0; }
                }
            }
            __syncthreads();
        }
    }

    float* ob = out;                              // boxes  16*100*4
    float* os = out + B_IMG * MAX_OUT_ * 4;       // scores 16*100
    float* oc = os + B_IMG * MAX_OUT_;            // cls    16*100
    float* on = oc + B_IMG * MAX_OUT_;            // n_valid 16

    unsigned int K = M < MAX_OUT_ ? M : MAX_OUT_;
    if (tid < MAX_OUT_) {
        if ((unsigned int)tid < K) {
            unsigned long long kk = keys[tid];
            unsigned int flat = ~((unsigned int)(kk & 0xFFFFFFFFull));
            float sv = __uint_as_float((unsigned int)(kk >> 32));
            const float* bp = cls_box + ((size_t)b * NC + flat) * 4;
            os[b * MAX_OUT_ + tid] = sv;
            oc[b * MAX_OUT_ + tid] = (float)(flat / MAX_OUT_);
            ob[(b * MAX_OUT_ + tid) * 4 + 0] = bp[0];
            ob[(b * MAX_OUT_ + tid) * 4 + 1] = bp[1];
            ob[(b * MAX_OUT_ + tid) * 4 + 2] = bp[2];
            ob[(b * MAX_OUT_ + tid) * 4 + 3] = bp[3];
        } else {
            os[b * MAX_OUT_ + tid] = 0.0f;
            oc[b * MAX_OUT_ + tid] = 0.0f;
            ob[(b * MAX_OUT_ + tid) * 4 + 0] = 0.0f;
            ob[(b * MAX_OUT_ + tid) * 4 + 1] = 0.0f;
            ob[(b * MAX_OUT_ + tid) * 4 + 2] = 0.0f;
            ob[(b * MAX_OUT_ + tid) * 4 + 3] = 0.0f;
        }
    }
    if (tid == 0) {
        unsigned int nv = s_tot < MAX_OUT_ ? s_tot : MAX_OUT_;
        on[b] = (float)nv;
    }
}

// ============================================================================
// FALLBACK PATH (round-1, known-correct) — used when ws_size is too small
// ============================================================================

__global__ void __launch_bounds__(256) decode_kernel(
    const float* __restrict__ p3, const float* __restrict__ p4,
    const float* __restrict__ p5, float* __restrict__ boxes,
    float* __restrict__ obj) {
    int gid = blockIdx.x * blockDim.x + threadIdx.x;
    if (gid >= B_IMG * N_ANCH) return;
    int b = gid / N_ANCH;
    int i = gid - b * N_ANCH;
    const float* p; int W, il, lvl; float stride;
    if (i < 19200)      { p = p3; W = 80; il = i;         lvl = 0; stride = 8.f;  }
    else if (i < 24000) { p = p4; W = 40; il = i - 19200; lvl = 1; stride = 16.f; }
    else                { p = p5; W = 20; il = i - 24000; lvl = 2; stride = 32.f; }
    int y = il / (W * 3);
    int t = il - y * W * 3;
    int x = t / 3;
    int a = t - x * 3;
    const float* q = p + ((((size_t)b * W + y) * W + x) * 255 + a * 85);
    float cx = (sigmoidf_(q[0]) + (float)x) * stride;
    float cy = (sigmoidf_(q[1]) + (float)y) * stride;
    float bw = expf(q[2]) * c_anch[lvl * 3 + a][0];
    float bh = expf(q[3]) * c_anch[lvl * 3 + a][1];
    float* bo = boxes + (size_t)gid * 4;
    bo[0] = cx - bw * 0.5f; bo[1] = cy - bh * 0.5f;
    bo[2] = cx + bw * 0.5f; bo[3] = cy + bh * 0.5f;
    obj[gid] = sigmoidf_(q[4]);
}

__device__ __forceinline__ float cand_score(
    const float* __restrict__ p3, const float* __restrict__ p4,
    const float* __restrict__ p5, const float* __restrict__ obj,
    int b, int c, int i) {
    const float* p; int W, il;
    if (i < 19200)      { p = p3; W = 80; il = i;         }
    else if (i < 24000) { p = p4; W = 40; il = i - 19200; }
    else                { p = p5; W = 20; il = i - 24000; }
    int y = il / (W * 3);
    int t = il - y * W * 3;
    int x = t / 3;
    int a = t - x * 3;
    float cl = p[(((size_t)b * W + y) * W + x) * 255 + a * 85 + 5 + c];
    return obj[b * N_ANCH + i] * sigmoidf_(cl);
}

__global__ void __launch_bounds__(256) topk_nms_kernel(
    const float* __restrict__ p3, const float* __restrict__ p4,
    const float* __restrict__ p5, const float* __restrict__ boxes,
    const float* __restrict__ obj, float* __restrict__ cls_score,
    float* __restrict__ cls_box) {
    int b = blockIdx.x / NUM_CLASSES;
    int c = blockIdx.x % NUM_CLASSES;
    int tid = threadIdx.x;

    __shared__ unsigned int hist[NBINS];
    __shared__ unsigned long long keys[CAP];
    __shared__ unsigned int s_cnt, s_cutoff;
    __shared__ float bx[NMS_TOPK_][5];
    __shared__ float bs[NMS_TOPK_];
    __shared__ int keep[NMS_TOPK_];

    for (int k = tid; k < NBINS; k += 256) hist[k] = 0u;
    if (tid == 0) s_cnt = 0u;
    __syncthreads();

    for (int i = tid; i < N_ANCH; i += 256) {
        float s = cand_score(p3, p4, p5, obj, b, c, i);
        if (s > SCORE_THR_) atomicAdd(&hist[score_bin(__float_as_uint(s))], 1u);
    }
    __syncthreads();

    if (tid == 0) {
        unsigned int total = 0;
        int cut = 0;
        for (int k = NBINS - 1; k >= 0; --k) {
            total += hist[k];
            if (total >= NMS_TOPK_) { cut = k; break; }
        }
        s_cutoff = (unsigned int)cut;
    }
    __syncthreads();
    unsigned int cutoff = s_cutoff;

    for (int i = tid; i < N_ANCH; i += 256) {
        float s = cand_score(p3, p4, p5, obj, b, c, i);
        if (s > SCORE_THR_) {
            unsigned int bits = __float_as_uint(s);
            if (score_bin(bits) >= cutoff) {
                unsigned int pos = atomicAdd(&s_cnt, 1u);
                if (pos < CAP) {
                    keys[pos] = ((unsigned long long)bits << 32) |
                                (unsigned long long)(~(unsigned int)i);
                }
            }
        }
    }
    __syncthreads();

    unsigned int M = s_cnt;
    if (M > CAP) M = CAP;
    unsigned int P2 = 1;
    while (P2 < M) P2 <<= 1;
    if (P2 < 2) P2 = 2;
    for (unsigned int k = M + tid; k < P2; k += 256) keys[k] = 0ull;
    __syncthreads();

    for (unsigned int k = 2; k <= P2; k <<= 1) {
        for (unsigned int j = k >> 1; j > 0; j >>= 1) {
            for (unsigned int t = tid; t < P2; t += 256) {
                unsigned int ixj = t ^ j;
                if (ixj > t) {
                    unsigned long long a0 = keys[t], b0 = keys[ixj];
                    bool desc = ((t & k) == 0);
                    if (desc ? (a0 < b0) : (a0 > b0)) { keys[t] = b0; keys[ixj] = a0; }
                }
            }
            __syncthreads();
        }
    }

    unsigned int K = M < NMS_TOPK_ ? M : NMS_TOPK_;
    if (tid < (int)K) {
        unsigned long long kk = keys[tid];
        unsigned int idx = ~((unsigned int)(kk & 0xFFFFFFFFull));
        const float* bp = boxes + ((size_t)b * N_ANCH + idx) * 4;
        bx[tid][0] = bp[0]; bx[tid][1] = bp[1];
        bx[tid][2] = bp[2]; bx[tid][3] = bp[3];
        bs[tid] = __uint_as_float((unsigned int)(kk >> 32));
        keep[tid] = 1;
    }
    __syncthreads();

    for (unsigned int i = 0; i < K; ++i) {
        if (keep[i]) {
            unsigned int t = (unsigned int)tid;
            if (t > i && t < K && keep[t]) {
                float ax0 = bx[i][0], ay0 = bx[i][1], ax1 = bx[i][2], ay1 = bx[i][3];
                float cx0 = bx[t][0], cy0 = bx[t][1], cx1 = bx[t][2], cy1 = bx[t][3];
                float areaA = (ax1 - ax0) * (ay1 - ay0);
                float areaB = (cx1 - cx0) * (cy1 - cy0);
                float lx = fmaxf(ax0, cx0), ly = fmaxf(ay0, cy0);
                float rx = fminf(ax1, cx1), ry = fminf(ay1, cy1);
                float w = rx - lx; if (w < 0.f) w = 0.f;
                float h = ry - ly; if (h < 0.f) h = 0.f;
                float inter = w * h;
                float iou = inter / (areaA + areaB - inter + 1e-9f);
                if (iou > IOU_THR_) keep[t] = 0;
            }
        }
        __syncthreads();
    }

    if (tid == 0) {
        float* scd = cls_score + ((size_t)b * NUM_CLASSES + c) * MAX_OUT_;
        float* bod = cls_box + ((size_t)b * NUM_CLASSES + c) * MAX_OUT_ * 4;
        int out_n = 0;
        for (unsigned int t2 = 0; t2 < K && out_n < MAX_OUT_; ++t2) {
            if (keep[t2]) {
                scd[out_n] = bs[t2];
                bod[out_n * 4 + 0] = bx[t2][0];
                bod[out_n * 4 + 1] = bx[t2][1];
                bod[out_n * 4 + 2] = bx[t2][2];
                bod[out_n * 4 + 3] = bx[t2][3];
                out_n++;
            }
        }
        for (; out_n < MAX_OUT_; ++out_n) {
            scd[out_n] = -1.0f;
            bod[out_n * 4 + 0] = 0.f; bod[out_n * 4 + 1] = 0.f;
            bod[out_n * 4 + 2] = 0.f; bod[out_n * 4 + 3] = 0.f;
        }
    }
}

extern "C" void kernel_launch(void* const* d_in, const int* in_sizes, int n_in,
                              void* d_out, int out_size, void* d_ws, size_t ws_size,
                              hipStream_t stream) {
    const float* p3 = (const float*)d_in[0];
    const float* p4 = (const float*)d_in[1];
    const float* p5 = (const float*)d_in[2];

    const size_t boxesB  = (size_t)B_IMG * N_ANCH * 4 * sizeof(float);          // 6,451,200
    const size_t clsSB   = (size_t)B_IMG * NUM_CLASSES * MAX_OUT_ * sizeof(float); // 512,000
    const size_t clsBB   = clsSB * 4;                                            // 2,048,000
    const size_t topselB = (size_t)B_IMG * NUM_CLASSES * NMS_TOPK_ * 8;          // 1,310,720
    const size_t scoreUB = (size_t)B_IMG * NUM_CLASSES * N_ANCH;                 // 32,256,000 (u8)
    const size_t need_new = boxesB + clsSB + clsBB + topselB + scoreUB;          // ~42.6 MB

    char* base = (char*)d_ws;

    if (ws_size >= need_new) {
        float* boxes     = (float*)base;
        float* cls_score = (float*)(base + boxesB);
        float* cls_box   = (float*)(base + boxesB + clsSB);
        unsigned long long* topsel =
            (unsigned long long*)(base + boxesB + clsSB + clsBB);
        unsigned char* score_u8 =
            (unsigned char*)(base + boxesB + clsSB + clsBB + topselB);

        decode_tile_kernel<<<B_IMG * TILES_PER_IMG, 256, 0, stream>>>(
            p3, p4, p5, boxes, score_u8);
        select_topk_u8_kernel<<<B_IMG * NUM_CLASSES, 256, 0, stream>>>(
            score_u8, p3, p4, p5, topsel);
        nms_kernel<<<B_IMG * NUM_CLASSES, 64, 0, stream>>>(
            topsel, boxes, cls_score, cls_box);
        final_fast_kernel<<<B_IMG, 256, 0, stream>>>(cls_score, cls_box, (float*)d_out);
    } else {
        float* boxes = (float*)base;
        float* obj = boxes + (size_t)B_IMG * N_ANCH * 4;
        float* cls_score = obj + (size_t)B_IMG * N_ANCH;
        float* cls_box = cls_score + (size_t)B_IMG * NUM_CLASSES * MAX_OUT_;

        int tot = B_IMG * N_ANCH;
        decode_kernel<<<(tot + 255) / 256, 256, 0, stream>>>(p3, p4, p5, boxes, obj);
        topk_nms_kernel<<<B_IMG * NUM_CLASSES, 256, 0, stream>>>(
            p3, p4, p5, boxes, obj, cls_score, cls_box);
        final_fast_kernel<<<B_IMG, 256, 0, stream>>>(cls_score, cls_box, (float*)d_out);
    }
}